// Round 1
// baseline (5500.361 us; speedup 1.0000x reference)
//
#include <hip/hip_runtime.h>
#include <math.h>

#define D_    1024
#define ED_   2048
#define NST   32
#define KCONV 4
#define DTR_  64
#define L_    1024
#define NB_   4

__device__ __forceinline__ float softplus_f(float x) {
  return x > 20.f ? x : log1pf(expf(x));
}
__device__ __forceinline__ float silu_f(float x) {
  return x / (1.f + expf(-x));
}

// C[M,N] = A[M,K](lda) @ W[N,K](ldw)^T   flags: 1=accumulate into C, 2=softplus, 4=bias
__global__ __launch_bounds__(256) void gemm_bt(
    const float* __restrict__ A, int lda,
    const float* __restrict__ W, int ldw,
    const float* __restrict__ bias,
    float* __restrict__ C, int ldc,
    int M, int N, int K, int flags)
{
  __shared__ float As[16][65];
  __shared__ float Ws[16][65];
  const int tid = threadIdx.x;
  const int row0 = blockIdx.y * 64, col0 = blockIdx.x * 64;
  const int tx = tid & 15, ty = tid >> 4;
  const int lm = tid >> 2, lk = (tid & 3) << 2;
  float acc[4][4] = {};
  for (int k0 = 0; k0 < K; k0 += 16) {
    float4 av = make_float4(0.f,0.f,0.f,0.f), wv = make_float4(0.f,0.f,0.f,0.f);
    if (row0 + lm < M && k0 + lk + 3 < K)
      av = *reinterpret_cast<const float4*>(A + (size_t)(row0 + lm) * lda + k0 + lk);
    if (col0 + lm < N && k0 + lk + 3 < K)
      wv = *reinterpret_cast<const float4*>(W + (size_t)(col0 + lm) * ldw + k0 + lk);
    __syncthreads();
    As[lk+0][lm]=av.x; As[lk+1][lm]=av.y; As[lk+2][lm]=av.z; As[lk+3][lm]=av.w;
    Ws[lk+0][lm]=wv.x; Ws[lk+1][lm]=wv.y; Ws[lk+2][lm]=wv.z; Ws[lk+3][lm]=wv.w;
    __syncthreads();
    #pragma unroll
    for (int k = 0; k < 16; ++k) {
      float a0 = As[k][ty*4+0], a1 = As[k][ty*4+1], a2 = As[k][ty*4+2], a3 = As[k][ty*4+3];
      float b0 = Ws[k][tx*4+0], b1 = Ws[k][tx*4+1], b2 = Ws[k][tx*4+2], b3 = Ws[k][tx*4+3];
      acc[0][0] += a0*b0; acc[0][1] += a0*b1; acc[0][2] += a0*b2; acc[0][3] += a0*b3;
      acc[1][0] += a1*b0; acc[1][1] += a1*b1; acc[1][2] += a1*b2; acc[1][3] += a1*b3;
      acc[2][0] += a2*b0; acc[2][1] += a2*b1; acc[2][2] += a2*b2; acc[2][3] += a2*b3;
      acc[3][0] += a3*b0; acc[3][1] += a3*b1; acc[3][2] += a3*b2; acc[3][3] += a3*b3;
    }
  }
  #pragma unroll
  for (int i = 0; i < 4; ++i) {
    int r = row0 + ty*4 + i;
    if (r >= M) continue;
    int c = col0 + tx*4;
    if (c >= N) continue;
    float4 v = make_float4(acc[i][0], acc[i][1], acc[i][2], acc[i][3]);
    if (flags & 4) {
      const float4 bv = *reinterpret_cast<const float4*>(bias + c);
      v.x += bv.x; v.y += bv.y; v.z += bv.z; v.w += bv.w;
    }
    if (flags & 2) { v.x=softplus_f(v.x); v.y=softplus_f(v.y); v.z=softplus_f(v.z); v.w=softplus_f(v.w); }
    float* cp = C + (size_t)r * ldc + c;
    if (flags & 1) {
      float4 ov = *reinterpret_cast<const float4*>(cp);
      v.x += ov.x; v.y += ov.y; v.z += ov.z; v.w += ov.w;
    }
    *reinterpret_cast<float4*>(cp) = v;
  }
}

// one block (256 thr) per row of 1024
__global__ __launch_bounds__(256) void layernorm_k(
    const float* __restrict__ x, const float* __restrict__ g,
    const float* __restrict__ b, float* __restrict__ out)
{
  __shared__ float red[8];
  const int row = blockIdx.x;
  const int tid = threadIdx.x;
  const float* xr = x + (size_t)row * D_;
  float4 v = *reinterpret_cast<const float4*>(xr + tid * 4);
  float s = v.x + v.y + v.z + v.w;
  #pragma unroll
  for (int off = 32; off; off >>= 1) s += __shfl_down(s, off, 64);
  if ((tid & 63) == 0) red[tid >> 6] = s;
  __syncthreads();
  const float m = (red[0] + red[1] + red[2] + red[3]) * (1.f / D_);
  float dx0 = v.x - m, dx1 = v.y - m, dx2 = v.z - m, dx3 = v.w - m;
  float ss = dx0*dx0 + dx1*dx1 + dx2*dx2 + dx3*dx3;
  #pragma unroll
  for (int off = 32; off; off >>= 1) ss += __shfl_down(ss, off, 64);
  if ((tid & 63) == 0) red[4 + (tid >> 6)] = ss;
  __syncthreads();
  const float var = (red[4] + red[5] + red[6] + red[7]) * (1.f / D_);
  const float rs = rsqrtf(var + 1e-5f);
  const int c = tid * 4;
  const float4 gv = *reinterpret_cast<const float4*>(g + c);
  const float4 bv = *reinterpret_cast<const float4*>(b + c);
  float4 o;
  o.x = dx0 * rs * gv.x + bv.x;
  o.y = dx1 * rs * gv.y + bv.y;
  o.z = dx2 * rs * gv.z + bv.z;
  o.w = dx3 * rs * gv.w + bv.w;
  *reinterpret_cast<float4*>(out + (size_t)row * D_ + c) = o;
}

// depthwise causal conv K=4 + bias + silu; xz row stride 2*ED_, u part cols [0,ED_)
__global__ __launch_bounds__(256) void conv_silu_k(
    const float* __restrict__ xz, const float* __restrict__ cw,
    const float* __restrict__ cb, float* __restrict__ u)
{
  const int e = blockIdx.x * 256 + threadIdx.x;
  const int t = blockIdx.y;
  const float w0 = cw[e*4+0], w1 = cw[e*4+1], w2 = cw[e*4+2], w3 = cw[e*4+3];
  float acc = cb[e];
  if (t >= 3) acc += w0 * xz[(size_t)(t-3) * (2*ED_) + e];
  if (t >= 2) acc += w1 * xz[(size_t)(t-2) * (2*ED_) + e];
  if (t >= 1) acc += w2 * xz[(size_t)(t-1) * (2*ED_) + e];
  acc += w3 * xz[(size_t)t * (2*ED_) + e];
  u[(size_t)t * ED_ + e] = silu_f(acc);
}

// selective scan: thread = (e, n); n = lane&31; 8 channels per 256-thr block
__global__ __launch_bounds__(256) void scan_k(
    const float* __restrict__ delta, const float* __restrict__ u,
    const float* __restrict__ xdbl, const float* __restrict__ A_log,
    const float* __restrict__ Dp, const float* __restrict__ xz,
    float* __restrict__ y)
{
  const int tid = threadIdx.x;
  const int n = tid & 31;
  const int c = tid >> 5;
  const int e = blockIdx.x * 8 + c;
  const float a = -expf(A_log[e * NST + n]);
  const float dp = Dp[e];
  float h = 0.f;
  for (int t = 0; t < L_; ++t) {
    const float sd = delta[(size_t)t * ED_ + e];
    const float uv = u[(size_t)t * ED_ + e];
    const float Bv = xdbl[(size_t)t * 128 + 64 + n];
    const float Cv = xdbl[(size_t)t * 128 + 96 + n];
    const float dA = expf(sd * a);
    h = dA * h + (sd * uv) * Bv;
    float p = h * Cv;
    #pragma unroll
    for (int off = 16; off; off >>= 1) p += __shfl_xor(p, off, 64);
    if (n == 0) {
      const float zv = xz[(size_t)t * (2*ED_) + ED_ + e];
      y[(size_t)t * ED_ + e] = (p + uv * dp) * silu_f(zv);
    }
  }
}

__global__ __launch_bounds__(256) void colmean_k(const float* __restrict__ hf, float* __restrict__ cm)
{
  const int d = blockIdx.x * 256 + threadIdx.x;
  float s = 0.f;
  for (int t = 0; t < L_; ++t) s += hf[(size_t)t * D_ + d];
  cm[d] = s * (1.f / L_);
}

__global__ __launch_bounds__(256) void state_k(
    const float* __restrict__ cm, const float* __restrict__ spw,
    const float* __restrict__ spb, float* __restrict__ out)
{
  __shared__ float red[4];
  const int nidx = blockIdx.x;
  const int tid = threadIdx.x;
  float s = 0.f;
  for (int d = tid; d < D_; d += 256) s += cm[d] * spw[(size_t)nidx * D_ + d];
  #pragma unroll
  for (int off = 32; off; off >>= 1) s += __shfl_down(s, off, 64);
  if ((tid & 63) == 0) red[tid >> 6] = s;
  __syncthreads();
  if (tid == 0) out[nidx] = red[0] + red[1] + red[2] + red[3] + spb[nidx];
}

extern "C" void kernel_launch(void* const* d_in, const int* in_sizes, int n_in,
                              void* d_out, int out_size, void* d_ws, size_t ws_size,
                              hipStream_t stream) {
  const float* x        = (const float*)d_in[0];
  const float* Wi       = (const float*)d_in[1];
  const float* bi       = (const float*)d_in[2];
  const float* ln_g     = (const float*)d_in[3];
  const float* ln_b     = (const float*)d_in[4];
  const float* in_w     = (const float*)d_in[5];
  const float* conv_w   = (const float*)d_in[6];
  const float* conv_b   = (const float*)d_in[7];
  const float* xproj_w  = (const float*)d_in[8];
  const float* dtproj_w = (const float*)d_in[9];
  const float* dtproj_b = (const float*)d_in[10];
  const float* A_log    = (const float*)d_in[11];
  const float* Dp       = (const float*)d_in[12];
  const float* out_w    = (const float*)d_in[13];
  const float* fn_g     = (const float*)d_in[14];
  const float* fn_b     = (const float*)d_in[15];
  const float* sp_w     = (const float*)d_in[16];
  const float* sp_b     = (const float*)d_in[17];
  float* out  = (float*)d_out;
  float* ws_f = (float*)d_ws;

  float* h_buf  = ws_f;               // 1024*1024
  float* normed = ws_f + 1048576;     // 1024*1024
  float* xz     = ws_f + 2097152;     // 1024*4096
  float* u_buf  = ws_f + 6291456;     // 1024*2048
  float* xdbl   = ws_f + 8388608;     // 1024*128
  float* delta  = ws_f + 8519680;     // 1024*2048
  float* y_buf  = ws_f + 10616832;    // 1024*2048
  float* cmean  = ws_f + 12713984;    // 1024

  const dim3 blk(256);

  // h = x @ Wi^T + bi
  gemm_bt<<<dim3(D_/64, L_/64), blk, 0, stream>>>(x, D_, Wi, D_, bi, h_buf, D_, L_, D_, D_, 4);

  for (int i = 0; i < NB_; ++i) {
    layernorm_k<<<L_, blk, 0, stream>>>(h_buf, ln_g + i*D_, ln_b + i*D_, normed);
    // xz = normed @ in_w^T
    gemm_bt<<<dim3(2*ED_/64, L_/64), blk, 0, stream>>>(
        normed, D_, in_w + (size_t)i*2*ED_*D_, D_, nullptr, xz, 2*ED_, L_, 2*ED_, D_, 0);
    conv_silu_k<<<dim3(ED_/256, L_), blk, 0, stream>>>(
        xz, conv_w + (size_t)i*ED_*KCONV, conv_b + (size_t)i*ED_, u_buf);
    // x_dbl = u @ xproj^T  (N=128)
    gemm_bt<<<dim3(128/64, L_/64), blk, 0, stream>>>(
        u_buf, ED_, xproj_w + (size_t)i*128*ED_, ED_, nullptr, xdbl, 128, L_, 128, ED_, 0);
    // delta = softplus(dt @ dtproj^T + b)  (A = xdbl cols [0,64), lda=128)
    gemm_bt<<<dim3(ED_/64, L_/64), blk, 0, stream>>>(
        xdbl, 128, dtproj_w + (size_t)i*ED_*DTR_, DTR_, dtproj_b + (size_t)i*ED_,
        delta, ED_, L_, ED_, DTR_, 4 | 2);
    scan_k<<<ED_/8, blk, 0, stream>>>(
        delta, u_buf, xdbl, A_log + (size_t)i*ED_*NST, Dp + (size_t)i*ED_, xz, y_buf);
    // h += y @ out_w^T
    gemm_bt<<<dim3(D_/64, L_/64), blk, 0, stream>>>(
        y_buf, ED_, out_w + (size_t)i*D_*ED_, ED_, nullptr, h_buf, D_, L_, D_, ED_, 1);
  }

  layernorm_k<<<L_, blk, 0, stream>>>(h_buf, fn_g, fn_b, out);
  colmean_k<<<D_/256, blk, 0, stream>>>(out, cmean);
  state_k<<<NST, blk, 0, stream>>>(cmean, sp_w, sp_b, out + (size_t)L_*D_);
}

// Round 2
// 2799.201 us; speedup vs baseline: 1.9650x; 1.9650x over previous
//
#include <hip/hip_runtime.h>
#include <math.h>

#define D_    1024
#define ED_   2048
#define NST   32
#define KCONV 4
#define DTR_  64
#define L_    1024
#define NB_   4
#define NCH   8
#define CHUNK (L_ / NCH)

__device__ __forceinline__ float softplus_f(float x) {
  return x > 20.f ? x : log1pf(expf(x));
}
__device__ __forceinline__ float silu_f(float x) {
  return x / (1.f + expf(-x));
}

// C[M,N] = A[M,K](lda) @ W[N,K](ldw)^T   flags: 1=accumulate into C, 2=softplus, 4=bias
__global__ __launch_bounds__(256) void gemm_bt(
    const float* __restrict__ A, int lda,
    const float* __restrict__ W, int ldw,
    const float* __restrict__ bias,
    float* __restrict__ C, int ldc,
    int M, int N, int K, int flags)
{
  __shared__ float As[16][65];
  __shared__ float Ws[16][65];
  const int tid = threadIdx.x;
  const int row0 = blockIdx.y * 64, col0 = blockIdx.x * 64;
  const int tx = tid & 15, ty = tid >> 4;
  const int lm = tid >> 2, lk = (tid & 3) << 2;
  float acc[4][4] = {};
  for (int k0 = 0; k0 < K; k0 += 16) {
    float4 av = make_float4(0.f,0.f,0.f,0.f), wv = make_float4(0.f,0.f,0.f,0.f);
    if (row0 + lm < M && k0 + lk + 3 < K)
      av = *reinterpret_cast<const float4*>(A + (size_t)(row0 + lm) * lda + k0 + lk);
    if (col0 + lm < N && k0 + lk + 3 < K)
      wv = *reinterpret_cast<const float4*>(W + (size_t)(col0 + lm) * ldw + k0 + lk);
    __syncthreads();
    As[lk+0][lm]=av.x; As[lk+1][lm]=av.y; As[lk+2][lm]=av.z; As[lk+3][lm]=av.w;
    Ws[lk+0][lm]=wv.x; Ws[lk+1][lm]=wv.y; Ws[lk+2][lm]=wv.z; Ws[lk+3][lm]=wv.w;
    __syncthreads();
    #pragma unroll
    for (int k = 0; k < 16; ++k) {
      float a0 = As[k][ty*4+0], a1 = As[k][ty*4+1], a2 = As[k][ty*4+2], a3 = As[k][ty*4+3];
      float b0 = Ws[k][tx*4+0], b1 = Ws[k][tx*4+1], b2 = Ws[k][tx*4+2], b3 = Ws[k][tx*4+3];
      acc[0][0] += a0*b0; acc[0][1] += a0*b1; acc[0][2] += a0*b2; acc[0][3] += a0*b3;
      acc[1][0] += a1*b0; acc[1][1] += a1*b1; acc[1][2] += a1*b2; acc[1][3] += a1*b3;
      acc[2][0] += a2*b0; acc[2][1] += a2*b1; acc[2][2] += a2*b2; acc[2][3] += a2*b3;
      acc[3][0] += a3*b0; acc[3][1] += a3*b1; acc[3][2] += a3*b2; acc[3][3] += a3*b3;
    }
  }
  #pragma unroll
  for (int i = 0; i < 4; ++i) {
    int r = row0 + ty*4 + i;
    if (r >= M) continue;
    int c = col0 + tx*4;
    if (c >= N) continue;
    float4 v = make_float4(acc[i][0], acc[i][1], acc[i][2], acc[i][3]);
    if (flags & 4) {
      const float4 bv = *reinterpret_cast<const float4*>(bias + c);
      v.x += bv.x; v.y += bv.y; v.z += bv.z; v.w += bv.w;
    }
    if (flags & 2) { v.x=softplus_f(v.x); v.y=softplus_f(v.y); v.z=softplus_f(v.z); v.w=softplus_f(v.w); }
    float* cp = C + (size_t)r * ldc + c;
    if (flags & 1) {
      float4 ov = *reinterpret_cast<const float4*>(cp);
      v.x += ov.x; v.y += ov.y; v.z += ov.z; v.w += ov.w;
    }
    *reinterpret_cast<float4*>(cp) = v;
  }
}

// one block (256 thr) per row of 1024
__global__ __launch_bounds__(256) void layernorm_k(
    const float* __restrict__ x, const float* __restrict__ g,
    const float* __restrict__ b, float* __restrict__ out)
{
  __shared__ float red[8];
  const int row = blockIdx.x;
  const int tid = threadIdx.x;
  const float* xr = x + (size_t)row * D_;
  float4 v = *reinterpret_cast<const float4*>(xr + tid * 4);
  float s = v.x + v.y + v.z + v.w;
  #pragma unroll
  for (int off = 32; off; off >>= 1) s += __shfl_down(s, off, 64);
  if ((tid & 63) == 0) red[tid >> 6] = s;
  __syncthreads();
  const float m = (red[0] + red[1] + red[2] + red[3]) * (1.f / D_);
  float dx0 = v.x - m, dx1 = v.y - m, dx2 = v.z - m, dx3 = v.w - m;
  float ss = dx0*dx0 + dx1*dx1 + dx2*dx2 + dx3*dx3;
  #pragma unroll
  for (int off = 32; off; off >>= 1) ss += __shfl_down(ss, off, 64);
  if ((tid & 63) == 0) red[4 + (tid >> 6)] = ss;
  __syncthreads();
  const float var = (red[4] + red[5] + red[6] + red[7]) * (1.f / D_);
  const float rs = rsqrtf(var + 1e-5f);
  const int c = tid * 4;
  const float4 gv = *reinterpret_cast<const float4*>(g + c);
  const float4 bv = *reinterpret_cast<const float4*>(b + c);
  float4 o;
  o.x = dx0 * rs * gv.x + bv.x;
  o.y = dx1 * rs * gv.y + bv.y;
  o.z = dx2 * rs * gv.z + bv.z;
  o.w = dx3 * rs * gv.w + bv.w;
  *reinterpret_cast<float4*>(out + (size_t)row * D_ + c) = o;
}

// depthwise causal conv K=4 + bias + silu; xz row stride 2*ED_, u part cols [0,ED_)
__global__ __launch_bounds__(256) void conv_silu_k(
    const float* __restrict__ xz, const float* __restrict__ cw,
    const float* __restrict__ cb, float* __restrict__ u)
{
  const int e = blockIdx.x * 256 + threadIdx.x;
  const int t = blockIdx.y;
  const float w0 = cw[e*4+0], w1 = cw[e*4+1], w2 = cw[e*4+2], w3 = cw[e*4+3];
  float acc = cb[e];
  if (t >= 3) acc += w0 * xz[(size_t)(t-3) * (2*ED_) + e];
  if (t >= 2) acc += w1 * xz[(size_t)(t-2) * (2*ED_) + e];
  if (t >= 1) acc += w2 * xz[(size_t)(t-1) * (2*ED_) + e];
  acc += w3 * xz[(size_t)t * (2*ED_) + e];
  u[(size_t)t * ED_ + e] = silu_f(acc);
}

// ---- chunked selective scan ----
// phase 1: per-chunk local scan from h=0; store h_end and P_end = prod(dA)
__global__ __launch_bounds__(256) void scan_phase1(
    const float* __restrict__ delta, const float* __restrict__ u,
    const float* __restrict__ xdbl, const float* __restrict__ A_log,
    float* __restrict__ hend, float* __restrict__ Pend)
{
  const int tid = threadIdx.x;
  const int n = tid & 31;
  const int e = blockIdx.x * 8 + (tid >> 5);
  const int c = blockIdx.y;
  const float a = -expf(A_log[e * NST + n]);
  float h = 0.f, P = 1.f;
  const int t0 = c * CHUNK;
  #pragma unroll 4
  for (int t = t0; t < t0 + CHUNK; ++t) {
    const float sd = delta[(size_t)t * ED_ + e];
    const float uv = u[(size_t)t * ED_ + e];
    const float Bv = xdbl[(size_t)t * 128 + 64 + n];
    const float dA = __expf(sd * a);
    h = fmaf(dA, h, sd * uv * Bv);
    P *= dA;
  }
  const int idx = c * (ED_ * NST) + blockIdx.x * 256 + tid;
  hend[idx] = h;
  Pend[idx] = P;
}

// phase 2: sequential combine over chunks; writes h_in[c] IN PLACE over Pend[c]
__global__ __launch_bounds__(256) void scan_phase2(
    const float* __restrict__ hend, float* __restrict__ Pend_hin)
{
  const int idx = blockIdx.x * 256 + threadIdx.x;  // e*32+n
  float hc = 0.f;
  #pragma unroll
  for (int c = 0; c < NCH; ++c) {
    const int off = c * (ED_ * NST) + idx;
    const float P = Pend_hin[off];
    const float hn = hend[off];
    Pend_hin[off] = hc;           // h_in for chunk c
    hc = fmaf(P, hc, hn);
  }
}

// phase 3: re-scan chunk from true h_in, reduce over n, gate, write y
__global__ __launch_bounds__(256) void scan_phase3(
    const float* __restrict__ delta, const float* __restrict__ u,
    const float* __restrict__ xdbl, const float* __restrict__ A_log,
    const float* __restrict__ hin, const float* __restrict__ Dp,
    const float* __restrict__ xz, float* __restrict__ y)
{
  const int tid = threadIdx.x;
  const int n = tid & 31;
  const int e = blockIdx.x * 8 + (tid >> 5);
  const int c = blockIdx.y;
  const float a = -expf(A_log[e * NST + n]);
  const float dp = Dp[e];
  float h = hin[c * (ED_ * NST) + blockIdx.x * 256 + tid];
  const int t0 = c * CHUNK;
  #pragma unroll 2
  for (int t = t0; t < t0 + CHUNK; ++t) {
    const float sd = delta[(size_t)t * ED_ + e];
    const float uv = u[(size_t)t * ED_ + e];
    const float Bv = xdbl[(size_t)t * 128 + 64 + n];
    const float Cv = xdbl[(size_t)t * 128 + 96 + n];
    const float dA = __expf(sd * a);
    h = fmaf(dA, h, sd * uv * Bv);
    float p = h * Cv;
    #pragma unroll
    for (int off = 16; off; off >>= 1) p += __shfl_xor(p, off, 64);
    if (n == 0) {
      const float zv = xz[(size_t)t * (2*ED_) + ED_ + e];
      y[(size_t)t * ED_ + e] = (p + uv * dp) * silu_f(zv);
    }
  }
}

__global__ __launch_bounds__(256) void colmean_k(const float* __restrict__ hf, float* __restrict__ cm)
{
  const int d = blockIdx.x * 256 + threadIdx.x;
  float s = 0.f;
  for (int t = 0; t < L_; ++t) s += hf[(size_t)t * D_ + d];
  cm[d] = s * (1.f / L_);
}

__global__ __launch_bounds__(256) void state_k(
    const float* __restrict__ cm, const float* __restrict__ spw,
    const float* __restrict__ spb, float* __restrict__ out)
{
  __shared__ float red[4];
  const int nidx = blockIdx.x;
  const int tid = threadIdx.x;
  float s = 0.f;
  for (int d = tid; d < D_; d += 256) s += cm[d] * spw[(size_t)nidx * D_ + d];
  #pragma unroll
  for (int off = 32; off; off >>= 1) s += __shfl_down(s, off, 64);
  if ((tid & 63) == 0) red[tid >> 6] = s;
  __syncthreads();
  if (tid == 0) out[nidx] = red[0] + red[1] + red[2] + red[3] + spb[nidx];
}

extern "C" void kernel_launch(void* const* d_in, const int* in_sizes, int n_in,
                              void* d_out, int out_size, void* d_ws, size_t ws_size,
                              hipStream_t stream) {
  const float* x        = (const float*)d_in[0];
  const float* Wi       = (const float*)d_in[1];
  const float* bi       = (const float*)d_in[2];
  const float* ln_g     = (const float*)d_in[3];
  const float* ln_b     = (const float*)d_in[4];
  const float* in_w     = (const float*)d_in[5];
  const float* conv_w   = (const float*)d_in[6];
  const float* conv_b   = (const float*)d_in[7];
  const float* xproj_w  = (const float*)d_in[8];
  const float* dtproj_w = (const float*)d_in[9];
  const float* dtproj_b = (const float*)d_in[10];
  const float* A_log    = (const float*)d_in[11];
  const float* Dp       = (const float*)d_in[12];
  const float* out_w    = (const float*)d_in[13];
  const float* fn_g     = (const float*)d_in[14];
  const float* fn_b     = (const float*)d_in[15];
  const float* sp_w     = (const float*)d_in[16];
  const float* sp_b     = (const float*)d_in[17];
  float* out  = (float*)d_out;
  float* ws_f = (float*)d_ws;

  float* h_buf  = ws_f;               // 1024*1024
  float* normed = ws_f + 1048576;     // 1024*1024 (dead during scan -> reused)
  float* xz     = ws_f + 2097152;     // 1024*4096
  float* u_buf  = ws_f + 6291456;     // 1024*2048
  float* xdbl   = ws_f + 8388608;     // 1024*128
  float* delta  = ws_f + 8519680;     // 1024*2048
  float* y_buf  = ws_f + 10616832;    // 1024*2048
  float* cmean  = ws_f + 12713984;    // 1024
  // scan carry buffers overlay `normed` (dead after xz GEMM within a block)
  float* hend   = normed;             // NCH*ED*NST = 524288
  float* pend   = normed + 524288;    // 524288 ; becomes h_in after phase 2

  const dim3 blk(256);

  // h = x @ Wi^T + bi
  gemm_bt<<<dim3(D_/64, L_/64), blk, 0, stream>>>(x, D_, Wi, D_, bi, h_buf, D_, L_, D_, D_, 4);

  for (int i = 0; i < NB_; ++i) {
    layernorm_k<<<L_, blk, 0, stream>>>(h_buf, ln_g + i*D_, ln_b + i*D_, normed);
    // xz = normed @ in_w^T
    gemm_bt<<<dim3(2*ED_/64, L_/64), blk, 0, stream>>>(
        normed, D_, in_w + (size_t)i*2*ED_*D_, D_, nullptr, xz, 2*ED_, L_, 2*ED_, D_, 0);
    conv_silu_k<<<dim3(ED_/256, L_), blk, 0, stream>>>(
        xz, conv_w + (size_t)i*ED_*KCONV, conv_b + (size_t)i*ED_, u_buf);
    // x_dbl = u @ xproj^T  (N=128)
    gemm_bt<<<dim3(128/64, L_/64), blk, 0, stream>>>(
        u_buf, ED_, xproj_w + (size_t)i*128*ED_, ED_, nullptr, xdbl, 128, L_, 128, ED_, 0);
    // delta = softplus(dt @ dtproj^T + b)
    gemm_bt<<<dim3(ED_/64, L_/64), blk, 0, stream>>>(
        xdbl, 128, dtproj_w + (size_t)i*ED_*DTR_, DTR_, dtproj_b + (size_t)i*ED_,
        delta, ED_, L_, ED_, DTR_, 4 | 2);
    // chunked scan
    scan_phase1<<<dim3(ED_/8, NCH), blk, 0, stream>>>(
        delta, u_buf, xdbl, A_log + (size_t)i*ED_*NST, hend, pend);
    scan_phase2<<<dim3(ED_*NST/256), blk, 0, stream>>>(hend, pend);
    scan_phase3<<<dim3(ED_/8, NCH), blk, 0, stream>>>(
        delta, u_buf, xdbl, A_log + (size_t)i*ED_*NST, pend,
        Dp + (size_t)i*ED_, xz, y_buf);
    // h += y @ out_w^T
    gemm_bt<<<dim3(D_/64, L_/64), blk, 0, stream>>>(
        y_buf, ED_, out_w + (size_t)i*D_*ED_, ED_, nullptr, h_buf, D_, L_, D_, ED_, 1);
  }

  layernorm_k<<<L_, blk, 0, stream>>>(h_buf, fn_g, fn_b, out);
  colmean_k<<<D_/256, blk, 0, stream>>>(out, cmean);
  state_k<<<NST, blk, 0, stream>>>(cmean, sp_w, sp_b, out + (size_t)L_*D_);
}

// Round 3
// 1763.557 us; speedup vs baseline: 3.1189x; 1.5872x over previous
//
#include <hip/hip_runtime.h>
#include <math.h>

#define D_    1024
#define ED_   2048
#define NST   32
#define KCONV 4
#define DTR_  64
#define L_    1024
#define NB_   4
#define NCH   8
#define CHUNK (L_ / NCH)

typedef __bf16 bf16_8 __attribute__((ext_vector_type(8)));
typedef __bf16 bf16_4 __attribute__((ext_vector_type(4)));
typedef float  f32x4  __attribute__((ext_vector_type(4)));

__device__ __forceinline__ float softplus_f(float x) {
  return x > 20.f ? x : log1pf(expf(x));
}
__device__ __forceinline__ float silu_f(float x) {
  return x / (1.f + expf(-x));
}

// fp32 -> bf16 (n multiple of 2048)
__global__ __launch_bounds__(256) void f2bf_k(
    const float* __restrict__ in, __bf16* __restrict__ out, int n)
{
  const int i = (blockIdx.x * 256 + threadIdx.x) * 8;
  if (i >= n) return;
  const float4 a = *reinterpret_cast<const float4*>(in + i);
  const float4 b = *reinterpret_cast<const float4*>(in + i + 4);
  bf16_8 v;
  v[0]=(__bf16)a.x; v[1]=(__bf16)a.y; v[2]=(__bf16)a.z; v[3]=(__bf16)a.w;
  v[4]=(__bf16)b.x; v[5]=(__bf16)b.y; v[6]=(__bf16)b.z; v[7]=(__bf16)b.w;
  *reinterpret_cast<bf16_8*>(out + i) = v;
}

// ---- MFMA bf16 GEMM: C[M,N] = A[M,K] @ W[N,K]^T ----
// 128x128 tile, BK=32, 4 waves, each wave 64x64 (4x4 frags of 16x16x32)
// flags: 1=accumulate into C, 4=bias
__global__ __launch_bounds__(256) void gemm_mfma(
    const __bf16* __restrict__ A, const __bf16* __restrict__ W,
    const float* __restrict__ bias, float* __restrict__ C, int ldc,
    int K, int flags)
{
  __shared__ __bf16 As[128 * 32];
  __shared__ __bf16 Ws[128 * 32];
  const int tid  = threadIdx.x;
  const int lane = tid & 63;
  const int w    = tid >> 6;
  const int wr   = w >> 1, wc = w & 1;
  const int row0 = blockIdx.y * 128, col0 = blockIdx.x * 128;

  f32x4 acc[4][4] = {};

  for (int k0 = 0; k0 < K; k0 += 32) {
    #pragma unroll
    for (int j = 0; j < 2; ++j) {
      const int inst = w * 2 + j;           // 0..7, wave-uniform
      const int eo   = inst * 512 + lane * 8;
      const int r    = eo >> 5, k = eo & 31;
      __builtin_amdgcn_global_load_lds(
          (const __attribute__((address_space(1))) void*)(A + (size_t)(row0 + r) * K + k0 + k),
          (__attribute__((address_space(3))) void*)(&As[inst * 512]), 16, 0, 0);
      __builtin_amdgcn_global_load_lds(
          (const __attribute__((address_space(1))) void*)(W + (size_t)(col0 + r) * K + k0 + k),
          (__attribute__((address_space(3))) void*)(&Ws[inst * 512]), 16, 0, 0);
    }
    __syncthreads();
    bf16_8 af[4], bfr[4];
    const int kk  = (lane >> 4) * 8;
    const int r16 = lane & 15;
    #pragma unroll
    for (int m = 0; m < 4; ++m)
      af[m] = *reinterpret_cast<const bf16_8*>(&As[(wr * 64 + m * 16 + r16) * 32 + kk]);
    #pragma unroll
    for (int n = 0; n < 4; ++n)
      bfr[n] = *reinterpret_cast<const bf16_8*>(&Ws[(wc * 64 + n * 16 + r16) * 32 + kk]);
    #pragma unroll
    for (int m = 0; m < 4; ++m)
      #pragma unroll
      for (int n = 0; n < 4; ++n)
        acc[m][n] = __builtin_amdgcn_mfma_f32_16x16x32_bf16(af[m], bfr[n], acc[m][n], 0, 0, 0);
    __syncthreads();
  }

  const int crow = (lane >> 4) * 4;
  const int ccol = lane & 15;
  #pragma unroll
  for (int m = 0; m < 4; ++m)
    #pragma unroll
    for (int n = 0; n < 4; ++n) {
      const int col = col0 + wc * 64 + n * 16 + ccol;
      const float bv = (flags & 4) ? bias[col] : 0.f;
      #pragma unroll
      for (int r = 0; r < 4; ++r) {
        const int row = row0 + wr * 64 + m * 16 + crow + r;
        float* cp = C + (size_t)row * ldc + col;
        float v = acc[m][n][r] + bv;
        if (flags & 1) v += *cp;
        *cp = v;
      }
    }
}

// fp32 GEMM kept for skinny shapes: C[M,N] = A @ W^T  flags: 1=acc, 2=softplus, 4=bias
__global__ __launch_bounds__(256) void gemm_bt(
    const float* __restrict__ A, int lda,
    const float* __restrict__ W, int ldw,
    const float* __restrict__ bias,
    float* __restrict__ C, int ldc,
    int M, int N, int K, int flags)
{
  __shared__ float As[16][65];
  __shared__ float Ws[16][65];
  const int tid = threadIdx.x;
  const int row0 = blockIdx.y * 64, col0 = blockIdx.x * 64;
  const int tx = tid & 15, ty = tid >> 4;
  const int lm = tid >> 2, lk = (tid & 3) << 2;
  float acc[4][4] = {};
  for (int k0 = 0; k0 < K; k0 += 16) {
    float4 av = make_float4(0.f,0.f,0.f,0.f), wv = make_float4(0.f,0.f,0.f,0.f);
    if (row0 + lm < M && k0 + lk + 3 < K)
      av = *reinterpret_cast<const float4*>(A + (size_t)(row0 + lm) * lda + k0 + lk);
    if (col0 + lm < N && k0 + lk + 3 < K)
      wv = *reinterpret_cast<const float4*>(W + (size_t)(col0 + lm) * ldw + k0 + lk);
    __syncthreads();
    As[lk+0][lm]=av.x; As[lk+1][lm]=av.y; As[lk+2][lm]=av.z; As[lk+3][lm]=av.w;
    Ws[lk+0][lm]=wv.x; Ws[lk+1][lm]=wv.y; Ws[lk+2][lm]=wv.z; Ws[lk+3][lm]=wv.w;
    __syncthreads();
    #pragma unroll
    for (int k = 0; k < 16; ++k) {
      float a0 = As[k][ty*4+0], a1 = As[k][ty*4+1], a2 = As[k][ty*4+2], a3 = As[k][ty*4+3];
      float b0 = Ws[k][tx*4+0], b1 = Ws[k][tx*4+1], b2 = Ws[k][tx*4+2], b3 = Ws[k][tx*4+3];
      acc[0][0] += a0*b0; acc[0][1] += a0*b1; acc[0][2] += a0*b2; acc[0][3] += a0*b3;
      acc[1][0] += a1*b0; acc[1][1] += a1*b1; acc[1][2] += a1*b2; acc[1][3] += a1*b3;
      acc[2][0] += a2*b0; acc[2][1] += a2*b1; acc[2][2] += a2*b2; acc[2][3] += a2*b3;
      acc[3][0] += a3*b0; acc[3][1] += a3*b1; acc[3][2] += a3*b2; acc[3][3] += a3*b3;
    }
  }
  #pragma unroll
  for (int i = 0; i < 4; ++i) {
    int r = row0 + ty*4 + i;
    if (r >= M) continue;
    int c = col0 + tx*4;
    if (c >= N) continue;
    float4 v = make_float4(acc[i][0], acc[i][1], acc[i][2], acc[i][3]);
    if (flags & 4) {
      const float4 bv = *reinterpret_cast<const float4*>(bias + c);
      v.x += bv.x; v.y += bv.y; v.z += bv.z; v.w += bv.w;
    }
    if (flags & 2) { v.x=softplus_f(v.x); v.y=softplus_f(v.y); v.z=softplus_f(v.z); v.w=softplus_f(v.w); }
    float* cp = C + (size_t)r * ldc + c;
    if (flags & 1) {
      float4 ov = *reinterpret_cast<const float4*>(cp);
      v.x += ov.x; v.y += ov.y; v.z += ov.z; v.w += ov.w;
    }
    *reinterpret_cast<float4*>(cp) = v;
  }
}

// layernorm, fp32 out (final LN)
__global__ __launch_bounds__(256) void layernorm_k(
    const float* __restrict__ x, const float* __restrict__ g,
    const float* __restrict__ b, float* __restrict__ out)
{
  __shared__ float red[8];
  const int row = blockIdx.x;
  const int tid = threadIdx.x;
  const float* xr = x + (size_t)row * D_;
  float4 v = *reinterpret_cast<const float4*>(xr + tid * 4);
  float s = v.x + v.y + v.z + v.w;
  #pragma unroll
  for (int off = 32; off; off >>= 1) s += __shfl_down(s, off, 64);
  if ((tid & 63) == 0) red[tid >> 6] = s;
  __syncthreads();
  const float m = (red[0] + red[1] + red[2] + red[3]) * (1.f / D_);
  float dx0 = v.x - m, dx1 = v.y - m, dx2 = v.z - m, dx3 = v.w - m;
  float ss = dx0*dx0 + dx1*dx1 + dx2*dx2 + dx3*dx3;
  #pragma unroll
  for (int off = 32; off; off >>= 1) ss += __shfl_down(ss, off, 64);
  if ((tid & 63) == 0) red[4 + (tid >> 6)] = ss;
  __syncthreads();
  const float var = (red[4] + red[5] + red[6] + red[7]) * (1.f / D_);
  const float rs = rsqrtf(var + 1e-5f);
  const int c = tid * 4;
  const float4 gv = *reinterpret_cast<const float4*>(g + c);
  const float4 bv = *reinterpret_cast<const float4*>(b + c);
  float4 o;
  o.x = dx0 * rs * gv.x + bv.x;
  o.y = dx1 * rs * gv.y + bv.y;
  o.z = dx2 * rs * gv.z + bv.z;
  o.w = dx3 * rs * gv.w + bv.w;
  *reinterpret_cast<float4*>(out + (size_t)row * D_ + c) = o;
}

// layernorm with bf16 out (feeds MFMA GEMM)
__global__ __launch_bounds__(256) void layernorm_bf_k(
    const float* __restrict__ x, const float* __restrict__ g,
    const float* __restrict__ b, __bf16* __restrict__ out)
{
  __shared__ float red[8];
  const int row = blockIdx.x;
  const int tid = threadIdx.x;
  const float* xr = x + (size_t)row * D_;
  float4 v = *reinterpret_cast<const float4*>(xr + tid * 4);
  float s = v.x + v.y + v.z + v.w;
  #pragma unroll
  for (int off = 32; off; off >>= 1) s += __shfl_down(s, off, 64);
  if ((tid & 63) == 0) red[tid >> 6] = s;
  __syncthreads();
  const float m = (red[0] + red[1] + red[2] + red[3]) * (1.f / D_);
  float dx0 = v.x - m, dx1 = v.y - m, dx2 = v.z - m, dx3 = v.w - m;
  float ss = dx0*dx0 + dx1*dx1 + dx2*dx2 + dx3*dx3;
  #pragma unroll
  for (int off = 32; off; off >>= 1) ss += __shfl_down(ss, off, 64);
  if ((tid & 63) == 0) red[4 + (tid >> 6)] = ss;
  __syncthreads();
  const float var = (red[4] + red[5] + red[6] + red[7]) * (1.f / D_);
  const float rs = rsqrtf(var + 1e-5f);
  const int c = tid * 4;
  const float4 gv = *reinterpret_cast<const float4*>(g + c);
  const float4 bv = *reinterpret_cast<const float4*>(b + c);
  bf16_4 o;
  o[0] = (__bf16)(dx0 * rs * gv.x + bv.x);
  o[1] = (__bf16)(dx1 * rs * gv.y + bv.y);
  o[2] = (__bf16)(dx2 * rs * gv.z + bv.z);
  o[3] = (__bf16)(dx3 * rs * gv.w + bv.w);
  *reinterpret_cast<bf16_4*>(out + (size_t)row * D_ + c) = o;
}

// depthwise causal conv K=4 + bias + silu
__global__ __launch_bounds__(256) void conv_silu_k(
    const float* __restrict__ xz, const float* __restrict__ cw,
    const float* __restrict__ cb, float* __restrict__ u)
{
  const int e = blockIdx.x * 256 + threadIdx.x;
  const int t = blockIdx.y;
  const float w0 = cw[e*4+0], w1 = cw[e*4+1], w2 = cw[e*4+2], w3 = cw[e*4+3];
  float acc = cb[e];
  if (t >= 3) acc += w0 * xz[(size_t)(t-3) * (2*ED_) + e];
  if (t >= 2) acc += w1 * xz[(size_t)(t-2) * (2*ED_) + e];
  if (t >= 1) acc += w2 * xz[(size_t)(t-1) * (2*ED_) + e];
  acc += w3 * xz[(size_t)t * (2*ED_) + e];
  u[(size_t)t * ED_ + e] = silu_f(acc);
}

// ---- chunked selective scan ----
__global__ __launch_bounds__(256) void scan_phase1(
    const float* __restrict__ delta, const float* __restrict__ u,
    const float* __restrict__ xdbl, const float* __restrict__ A_log,
    float* __restrict__ hend, float* __restrict__ Pend)
{
  const int tid = threadIdx.x;
  const int n = tid & 31;
  const int e = blockIdx.x * 8 + (tid >> 5);
  const int c = blockIdx.y;
  const float a = -expf(A_log[e * NST + n]);
  float h = 0.f, P = 1.f;
  const int t0 = c * CHUNK;
  #pragma unroll 4
  for (int t = t0; t < t0 + CHUNK; ++t) {
    const float sd = delta[(size_t)t * ED_ + e];
    const float uv = u[(size_t)t * ED_ + e];
    const float Bv = xdbl[(size_t)t * 128 + 64 + n];
    const float dA = __expf(sd * a);
    h = fmaf(dA, h, sd * uv * Bv);
    P *= dA;
  }
  const int idx = c * (ED_ * NST) + blockIdx.x * 256 + tid;
  hend[idx] = h;
  Pend[idx] = P;
}

__global__ __launch_bounds__(256) void scan_phase2(
    const float* __restrict__ hend, float* __restrict__ Pend_hin)
{
  const int idx = blockIdx.x * 256 + threadIdx.x;
  float hc = 0.f;
  #pragma unroll
  for (int c = 0; c < NCH; ++c) {
    const int off = c * (ED_ * NST) + idx;
    const float P = Pend_hin[off];
    const float hn = hend[off];
    Pend_hin[off] = hc;
    hc = fmaf(P, hc, hn);
  }
}

// phase 3: re-scan from true h_in; writes y as bf16 (feeds MFMA out-GEMM)
__global__ __launch_bounds__(256) void scan_phase3(
    const float* __restrict__ delta, const float* __restrict__ u,
    const float* __restrict__ xdbl, const float* __restrict__ A_log,
    const float* __restrict__ hin, const float* __restrict__ Dp,
    const float* __restrict__ xz, __bf16* __restrict__ y)
{
  const int tid = threadIdx.x;
  const int n = tid & 31;
  const int e = blockIdx.x * 8 + (tid >> 5);
  const int c = blockIdx.y;
  const float a = -expf(A_log[e * NST + n]);
  const float dp = Dp[e];
  float h = hin[c * (ED_ * NST) + blockIdx.x * 256 + tid];
  const int t0 = c * CHUNK;
  #pragma unroll 2
  for (int t = t0; t < t0 + CHUNK; ++t) {
    const float sd = delta[(size_t)t * ED_ + e];
    const float uv = u[(size_t)t * ED_ + e];
    const float Bv = xdbl[(size_t)t * 128 + 64 + n];
    const float Cv = xdbl[(size_t)t * 128 + 96 + n];
    const float dA = __expf(sd * a);
    h = fmaf(dA, h, sd * uv * Bv);
    float p = h * Cv;
    #pragma unroll
    for (int off = 16; off; off >>= 1) p += __shfl_xor(p, off, 64);
    if (n == 0) {
      const float zv = xz[(size_t)t * (2*ED_) + ED_ + e];
      y[(size_t)t * ED_ + e] = (__bf16)((p + uv * dp) * silu_f(zv));
    }
  }
}

__global__ __launch_bounds__(256) void colmean_k(const float* __restrict__ hf, float* __restrict__ cm)
{
  const int d = blockIdx.x * 256 + threadIdx.x;
  float s = 0.f;
  for (int t = 0; t < L_; ++t) s += hf[(size_t)t * D_ + d];
  cm[d] = s * (1.f / L_);
}

__global__ __launch_bounds__(256) void state_k(
    const float* __restrict__ cm, const float* __restrict__ spw,
    const float* __restrict__ spb, float* __restrict__ out)
{
  __shared__ float red[4];
  const int nidx = blockIdx.x;
  const int tid = threadIdx.x;
  float s = 0.f;
  for (int d = tid; d < D_; d += 256) s += cm[d] * spw[(size_t)nidx * D_ + d];
  #pragma unroll
  for (int off = 32; off; off >>= 1) s += __shfl_down(s, off, 64);
  if ((tid & 63) == 0) red[tid >> 6] = s;
  __syncthreads();
  if (tid == 0) out[nidx] = red[0] + red[1] + red[2] + red[3] + spb[nidx];
}

extern "C" void kernel_launch(void* const* d_in, const int* in_sizes, int n_in,
                              void* d_out, int out_size, void* d_ws, size_t ws_size,
                              hipStream_t stream) {
  const float* x        = (const float*)d_in[0];
  const float* Wi       = (const float*)d_in[1];
  const float* bi       = (const float*)d_in[2];
  const float* ln_g     = (const float*)d_in[3];
  const float* ln_b     = (const float*)d_in[4];
  const float* in_w     = (const float*)d_in[5];
  const float* conv_w   = (const float*)d_in[6];
  const float* conv_b   = (const float*)d_in[7];
  const float* xproj_w  = (const float*)d_in[8];
  const float* dtproj_w = (const float*)d_in[9];
  const float* dtproj_b = (const float*)d_in[10];
  const float* A_log    = (const float*)d_in[11];
  const float* Dp       = (const float*)d_in[12];
  const float* out_w    = (const float*)d_in[13];
  const float* fn_g     = (const float*)d_in[14];
  const float* fn_b     = (const float*)d_in[15];
  const float* sp_w     = (const float*)d_in[16];
  const float* sp_b     = (const float*)d_in[17];
  float* out  = (float*)d_out;
  float* ws_f = (float*)d_ws;

  float* h_buf  = ws_f;                // 1048576
  float* xz     = ws_f + 1048576;      // 4194304
  float* u_buf  = ws_f + 5242880;      // 2097152
  float* xdbl   = ws_f + 7340032;      // 131072
  float* delta  = ws_f + 7471104;      // 2097152
  float* hend   = ws_f + 9568256;      // 524288
  float* pend   = ws_f + 10092544;     // 524288
  float* cmean  = ws_f + 10616832;     // 1024
  __bf16* nbf   = (__bf16*)(ws_f + 10617856);  // 1M bf16 (normed / x)
  __bf16* ybf   = (__bf16*)(ws_f + 11142144);  // 2M bf16 (y)
  __bf16* wbf   = (__bf16*)(ws_f + 12190720);  // 4.19M bf16 (weights)

  const dim3 blk(256);

  // h = x @ Wi^T + bi   (bf16 MFMA)
  f2bf_k<<<512, blk, 0, stream>>>(x, nbf, L_ * D_);
  f2bf_k<<<512, blk, 0, stream>>>(Wi, wbf, D_ * D_);
  gemm_mfma<<<dim3(D_/128, L_/128), blk, 0, stream>>>(nbf, wbf, bi, h_buf, D_, D_, 4);

  for (int i = 0; i < NB_; ++i) {
    layernorm_bf_k<<<L_, blk, 0, stream>>>(h_buf, ln_g + i*D_, ln_b + i*D_, nbf);
    // xz = normed @ in_w^T
    f2bf_k<<<2048, blk, 0, stream>>>(in_w + (size_t)i*2*ED_*D_, wbf, 2*ED_*D_);
    gemm_mfma<<<dim3(2*ED_/128, L_/128), blk, 0, stream>>>(nbf, wbf, nullptr, xz, 2*ED_, D_, 0);
    conv_silu_k<<<dim3(ED_/256, L_), blk, 0, stream>>>(
        xz, conv_w + (size_t)i*ED_*KCONV, conv_b + (size_t)i*ED_, u_buf);
    // x_dbl = u @ xproj^T  (fp32, N=128)
    gemm_bt<<<dim3(128/64, L_/64), blk, 0, stream>>>(
        u_buf, ED_, xproj_w + (size_t)i*128*ED_, ED_, nullptr, xdbl, 128, L_, 128, ED_, 0);
    // delta = softplus(dt @ dtproj^T + b)  (fp32, K=64)
    gemm_bt<<<dim3(ED_/64, L_/64), blk, 0, stream>>>(
        xdbl, 128, dtproj_w + (size_t)i*ED_*DTR_, DTR_, dtproj_b + (size_t)i*ED_,
        delta, ED_, L_, ED_, DTR_, 4 | 2);
    // chunked scan
    scan_phase1<<<dim3(ED_/8, NCH), blk, 0, stream>>>(
        delta, u_buf, xdbl, A_log + (size_t)i*ED_*NST, hend, pend);
    scan_phase2<<<dim3(ED_*NST/256), blk, 0, stream>>>(hend, pend);
    scan_phase3<<<dim3(ED_/8, NCH), blk, 0, stream>>>(
        delta, u_buf, xdbl, A_log + (size_t)i*ED_*NST, pend,
        Dp + (size_t)i*ED_, xz, ybf);
    // h += y @ out_w^T   (bf16 MFMA accumulate)
    f2bf_k<<<1024, blk, 0, stream>>>(out_w + (size_t)i*D_*ED_, wbf, D_*ED_);
    gemm_mfma<<<dim3(D_/128, L_/128), blk, 0, stream>>>(ybf, wbf, nullptr, h_buf, D_, ED_, 1);
  }

  layernorm_k<<<L_, blk, 0, stream>>>(h_buf, fn_g, fn_b, out);
  colmean_k<<<D_/256, blk, 0, stream>>>(out, cmean);
  state_k<<<NST, blk, 0, stream>>>(cmean, sp_w, sp_b, out + (size_t)L_*D_);
}

// Round 4
// 1255.514 us; speedup vs baseline: 4.3810x; 1.4046x over previous
//
#include <hip/hip_runtime.h>
#include <math.h>

#define D_    1024
#define ED_   2048
#define NST   32
#define KCONV 4
#define DTR_  64
#define L_    1024
#define NB_   4
#define NCH   8
#define CHUNK (L_ / NCH)
#define KSPL  8

typedef __bf16 bf16_8 __attribute__((ext_vector_type(8)));
typedef __bf16 bf16_4 __attribute__((ext_vector_type(4)));
typedef float  f32x4  __attribute__((ext_vector_type(4)));

__device__ __forceinline__ float softplus_f(float x) {
  return x > 20.f ? x : log1pf(expf(x));
}
__device__ __forceinline__ float silu_f(float x) {
  return x / (1.f + expf(-x));
}

// fp32 -> bf16 (n multiple of 2048)
__global__ __launch_bounds__(256) void f2bf_k(
    const float* __restrict__ in, __bf16* __restrict__ out, int n)
{
  const int i = (blockIdx.x * 256 + threadIdx.x) * 8;
  if (i >= n) return;
  const float4 a = *reinterpret_cast<const float4*>(in + i);
  const float4 b = *reinterpret_cast<const float4*>(in + i + 4);
  bf16_8 v;
  v[0]=(__bf16)a.x; v[1]=(__bf16)a.y; v[2]=(__bf16)a.z; v[3]=(__bf16)a.w;
  v[4]=(__bf16)b.x; v[5]=(__bf16)b.y; v[6]=(__bf16)b.z; v[7]=(__bf16)b.w;
  *reinterpret_cast<bf16_8*>(out + i) = v;
}

// ---- MFMA bf16 GEMM: C[M,N] = A[M,K] @ W[N,K]^T ----
// 128x128 tile, BK=32, 4 waves, each wave 64x64 (4x4 frags of 16x16x32)
// flags: 1=accumulate into C, 4=bias
__global__ __launch_bounds__(256) void gemm_mfma(
    const __bf16* __restrict__ A, const __bf16* __restrict__ W,
    const float* __restrict__ bias, float* __restrict__ C, int ldc,
    int K, int flags)
{
  __shared__ __bf16 As[128 * 32];
  __shared__ __bf16 Ws[128 * 32];
  const int tid  = threadIdx.x;
  const int lane = tid & 63;
  const int w    = tid >> 6;
  const int wr   = w >> 1, wc = w & 1;
  const int row0 = blockIdx.y * 128, col0 = blockIdx.x * 128;

  f32x4 acc[4][4] = {};

  for (int k0 = 0; k0 < K; k0 += 32) {
    #pragma unroll
    for (int j = 0; j < 2; ++j) {
      const int inst = w * 2 + j;           // 0..7, wave-uniform
      const int eo   = inst * 512 + lane * 8;
      const int r    = eo >> 5, k = eo & 31;
      __builtin_amdgcn_global_load_lds(
          (const __attribute__((address_space(1))) void*)(A + (size_t)(row0 + r) * K + k0 + k),
          (__attribute__((address_space(3))) void*)(&As[inst * 512]), 16, 0, 0);
      __builtin_amdgcn_global_load_lds(
          (const __attribute__((address_space(1))) void*)(W + (size_t)(col0 + r) * K + k0 + k),
          (__attribute__((address_space(3))) void*)(&Ws[inst * 512]), 16, 0, 0);
    }
    __syncthreads();
    bf16_8 af[4], bfr[4];
    const int kk  = (lane >> 4) * 8;
    const int r16 = lane & 15;
    #pragma unroll
    for (int m = 0; m < 4; ++m)
      af[m] = *reinterpret_cast<const bf16_8*>(&As[(wr * 64 + m * 16 + r16) * 32 + kk]);
    #pragma unroll
    for (int n = 0; n < 4; ++n)
      bfr[n] = *reinterpret_cast<const bf16_8*>(&Ws[(wc * 64 + n * 16 + r16) * 32 + kk]);
    #pragma unroll
    for (int m = 0; m < 4; ++m)
      #pragma unroll
      for (int n = 0; n < 4; ++n)
        acc[m][n] = __builtin_amdgcn_mfma_f32_16x16x32_bf16(af[m], bfr[n], acc[m][n], 0, 0, 0);
    __syncthreads();
  }

  const int crow = (lane >> 4) * 4;
  const int ccol = lane & 15;
  #pragma unroll
  for (int m = 0; m < 4; ++m)
    #pragma unroll
    for (int n = 0; n < 4; ++n) {
      const int col = col0 + wc * 64 + n * 16 + ccol;
      const float bv = (flags & 4) ? bias[col] : 0.f;
      #pragma unroll
      for (int r = 0; r < 4; ++r) {
        const int row = row0 + wr * 64 + m * 16 + crow + r;
        float* cp = C + (size_t)row * ldc + col;
        float v = acc[m][n][r] + bv;
        if (flags & 1) v += *cp;
        *cp = v;
      }
    }
}

// fp32 GEMM: C[M,N] = A @ W^T  flags: 1=acc, 2=softplus, 4=bias
__global__ __launch_bounds__(256) void gemm_bt(
    const float* __restrict__ A, int lda,
    const float* __restrict__ W, int ldw,
    const float* __restrict__ bias,
    float* __restrict__ C, int ldc,
    int M, int N, int K, int flags)
{
  __shared__ float As[16][65];
  __shared__ float Ws[16][65];
  const int tid = threadIdx.x;
  const int row0 = blockIdx.y * 64, col0 = blockIdx.x * 64;
  const int tx = tid & 15, ty = tid >> 4;
  const int lm = tid >> 2, lk = (tid & 3) << 2;
  float acc[4][4] = {};
  for (int k0 = 0; k0 < K; k0 += 16) {
    float4 av = make_float4(0.f,0.f,0.f,0.f), wv = make_float4(0.f,0.f,0.f,0.f);
    if (row0 + lm < M && k0 + lk + 3 < K)
      av = *reinterpret_cast<const float4*>(A + (size_t)(row0 + lm) * lda + k0 + lk);
    if (col0 + lm < N && k0 + lk + 3 < K)
      wv = *reinterpret_cast<const float4*>(W + (size_t)(col0 + lm) * ldw + k0 + lk);
    __syncthreads();
    As[lk+0][lm]=av.x; As[lk+1][lm]=av.y; As[lk+2][lm]=av.z; As[lk+3][lm]=av.w;
    Ws[lk+0][lm]=wv.x; Ws[lk+1][lm]=wv.y; Ws[lk+2][lm]=wv.z; Ws[lk+3][lm]=wv.w;
    __syncthreads();
    #pragma unroll
    for (int k = 0; k < 16; ++k) {
      float a0 = As[k][ty*4+0], a1 = As[k][ty*4+1], a2 = As[k][ty*4+2], a3 = As[k][ty*4+3];
      float b0 = Ws[k][tx*4+0], b1 = Ws[k][tx*4+1], b2 = Ws[k][tx*4+2], b3 = Ws[k][tx*4+3];
      acc[0][0] += a0*b0; acc[0][1] += a0*b1; acc[0][2] += a0*b2; acc[0][3] += a0*b3;
      acc[1][0] += a1*b0; acc[1][1] += a1*b1; acc[1][2] += a1*b2; acc[1][3] += a1*b3;
      acc[2][0] += a2*b0; acc[2][1] += a2*b1; acc[2][2] += a2*b2; acc[2][3] += a2*b3;
      acc[3][0] += a3*b0; acc[3][1] += a3*b1; acc[3][2] += a3*b2; acc[3][3] += a3*b3;
    }
  }
  #pragma unroll
  for (int i = 0; i < 4; ++i) {
    int r = row0 + ty*4 + i;
    if (r >= M) continue;
    int c = col0 + tx*4;
    if (c >= N) continue;
    float4 v = make_float4(acc[i][0], acc[i][1], acc[i][2], acc[i][3]);
    if (flags & 4) {
      const float4 bv = *reinterpret_cast<const float4*>(bias + c);
      v.x += bv.x; v.y += bv.y; v.z += bv.z; v.w += bv.w;
    }
    if (flags & 2) { v.x=softplus_f(v.x); v.y=softplus_f(v.y); v.z=softplus_f(v.z); v.w=softplus_f(v.w); }
    float* cp = C + (size_t)r * ldc + c;
    if (flags & 1) {
      float4 ov = *reinterpret_cast<const float4*>(cp);
      v.x += ov.x; v.y += ov.y; v.z += ov.z; v.w += ov.w;
    }
    *reinterpret_cast<float4*>(cp) = v;
  }
}

// split-K fp32 GEMM: partials[z][M][N] = A[:, z*Kc:(z+1)*Kc] @ W^T chunk
// grid (N/64, M/64, KSPL); no flags.
__global__ __launch_bounds__(256) void gemm_bt_sk(
    const float* __restrict__ A, int lda,
    const float* __restrict__ W, int ldw,
    float* __restrict__ partials, int ldc,
    int M, int N, int K)
{
  __shared__ float As[16][65];
  __shared__ float Ws[16][65];
  const int tid = threadIdx.x;
  const int row0 = blockIdx.y * 64, col0 = blockIdx.x * 64;
  const int Kc = K / KSPL;
  const int kbase = blockIdx.z * Kc;
  const int tx = tid & 15, ty = tid >> 4;
  const int lm = tid >> 2, lk = (tid & 3) << 2;
  float acc[4][4] = {};
  for (int k0 = kbase; k0 < kbase + Kc; k0 += 16) {
    float4 av = *reinterpret_cast<const float4*>(A + (size_t)(row0 + lm) * lda + k0 + lk);
    float4 wv = *reinterpret_cast<const float4*>(W + (size_t)(col0 + lm) * ldw + k0 + lk);
    __syncthreads();
    As[lk+0][lm]=av.x; As[lk+1][lm]=av.y; As[lk+2][lm]=av.z; As[lk+3][lm]=av.w;
    Ws[lk+0][lm]=wv.x; Ws[lk+1][lm]=wv.y; Ws[lk+2][lm]=wv.z; Ws[lk+3][lm]=wv.w;
    __syncthreads();
    #pragma unroll
    for (int k = 0; k < 16; ++k) {
      float a0 = As[k][ty*4+0], a1 = As[k][ty*4+1], a2 = As[k][ty*4+2], a3 = As[k][ty*4+3];
      float b0 = Ws[k][tx*4+0], b1 = Ws[k][tx*4+1], b2 = Ws[k][tx*4+2], b3 = Ws[k][tx*4+3];
      acc[0][0] += a0*b0; acc[0][1] += a0*b1; acc[0][2] += a0*b2; acc[0][3] += a0*b3;
      acc[1][0] += a1*b0; acc[1][1] += a1*b1; acc[1][2] += a1*b2; acc[1][3] += a1*b3;
      acc[2][0] += a2*b0; acc[2][1] += a2*b1; acc[2][2] += a2*b2; acc[2][3] += a2*b3;
      acc[3][0] += a3*b0; acc[3][1] += a3*b1; acc[3][2] += a3*b2; acc[3][3] += a3*b3;
    }
  }
  float* base = partials + (size_t)blockIdx.z * M * ldc;
  #pragma unroll
  for (int i = 0; i < 4; ++i) {
    const int r = row0 + ty*4 + i;
    float4 v = make_float4(acc[i][0], acc[i][1], acc[i][2], acc[i][3]);
    *reinterpret_cast<float4*>(base + (size_t)r * ldc + col0 + tx*4) = v;
  }
}

// reduce KSPL partials -> C  (elements = M*N)
__global__ __launch_bounds__(256) void sk_reduce_k(
    const float* __restrict__ partials, float* __restrict__ C, int elems)
{
  const int i = (blockIdx.x * 256 + threadIdx.x) * 4;
  if (i >= elems) return;
  float4 s = *reinterpret_cast<const float4*>(partials + i);
  #pragma unroll
  for (int z = 1; z < KSPL; ++z) {
    const float4 p = *reinterpret_cast<const float4*>(partials + (size_t)z * elems + i);
    s.x += p.x; s.y += p.y; s.z += p.z; s.w += p.w;
  }
  *reinterpret_cast<float4*>(C + i) = s;
}

// layernorm, fp32 out (final LN)
__global__ __launch_bounds__(256) void layernorm_k(
    const float* __restrict__ x, const float* __restrict__ g,
    const float* __restrict__ b, float* __restrict__ out)
{
  __shared__ float red[8];
  const int row = blockIdx.x;
  const int tid = threadIdx.x;
  const float* xr = x + (size_t)row * D_;
  float4 v = *reinterpret_cast<const float4*>(xr + tid * 4);
  float s = v.x + v.y + v.z + v.w;
  #pragma unroll
  for (int off = 32; off; off >>= 1) s += __shfl_down(s, off, 64);
  if ((tid & 63) == 0) red[tid >> 6] = s;
  __syncthreads();
  const float m = (red[0] + red[1] + red[2] + red[3]) * (1.f / D_);
  float dx0 = v.x - m, dx1 = v.y - m, dx2 = v.z - m, dx3 = v.w - m;
  float ss = dx0*dx0 + dx1*dx1 + dx2*dx2 + dx3*dx3;
  #pragma unroll
  for (int off = 32; off; off >>= 1) ss += __shfl_down(ss, off, 64);
  if ((tid & 63) == 0) red[4 + (tid >> 6)] = ss;
  __syncthreads();
  const float var = (red[4] + red[5] + red[6] + red[7]) * (1.f / D_);
  const float rs = rsqrtf(var + 1e-5f);
  const int c = tid * 4;
  const float4 gv = *reinterpret_cast<const float4*>(g + c);
  const float4 bv = *reinterpret_cast<const float4*>(b + c);
  float4 o;
  o.x = dx0 * rs * gv.x + bv.x;
  o.y = dx1 * rs * gv.y + bv.y;
  o.z = dx2 * rs * gv.z + bv.z;
  o.w = dx3 * rs * gv.w + bv.w;
  *reinterpret_cast<float4*>(out + (size_t)row * D_ + c) = o;
}

// layernorm with bf16 out (feeds MFMA GEMM)
__global__ __launch_bounds__(256) void layernorm_bf_k(
    const float* __restrict__ x, const float* __restrict__ g,
    const float* __restrict__ b, __bf16* __restrict__ out)
{
  __shared__ float red[8];
  const int row = blockIdx.x;
  const int tid = threadIdx.x;
  const float* xr = x + (size_t)row * D_;
  float4 v = *reinterpret_cast<const float4*>(xr + tid * 4);
  float s = v.x + v.y + v.z + v.w;
  #pragma unroll
  for (int off = 32; off; off >>= 1) s += __shfl_down(s, off, 64);
  if ((tid & 63) == 0) red[tid >> 6] = s;
  __syncthreads();
  const float m = (red[0] + red[1] + red[2] + red[3]) * (1.f / D_);
  float dx0 = v.x - m, dx1 = v.y - m, dx2 = v.z - m, dx3 = v.w - m;
  float ss = dx0*dx0 + dx1*dx1 + dx2*dx2 + dx3*dx3;
  #pragma unroll
  for (int off = 32; off; off >>= 1) ss += __shfl_down(ss, off, 64);
  if ((tid & 63) == 0) red[4 + (tid >> 6)] = ss;
  __syncthreads();
  const float var = (red[4] + red[5] + red[6] + red[7]) * (1.f / D_);
  const float rs = rsqrtf(var + 1e-5f);
  const int c = tid * 4;
  const float4 gv = *reinterpret_cast<const float4*>(g + c);
  const float4 bv = *reinterpret_cast<const float4*>(b + c);
  bf16_4 o;
  o[0] = (__bf16)(dx0 * rs * gv.x + bv.x);
  o[1] = (__bf16)(dx1 * rs * gv.y + bv.y);
  o[2] = (__bf16)(dx2 * rs * gv.z + bv.z);
  o[3] = (__bf16)(dx3 * rs * gv.w + bv.w);
  *reinterpret_cast<bf16_4*>(out + (size_t)row * D_ + c) = o;
}

// depthwise causal conv K=4 + bias + silu
__global__ __launch_bounds__(256) void conv_silu_k(
    const float* __restrict__ xz, const float* __restrict__ cw,
    const float* __restrict__ cb, float* __restrict__ u)
{
  const int e = blockIdx.x * 256 + threadIdx.x;
  const int t = blockIdx.y;
  const float w0 = cw[e*4+0], w1 = cw[e*4+1], w2 = cw[e*4+2], w3 = cw[e*4+3];
  float acc = cb[e];
  if (t >= 3) acc += w0 * xz[(size_t)(t-3) * (2*ED_) + e];
  if (t >= 2) acc += w1 * xz[(size_t)(t-2) * (2*ED_) + e];
  if (t >= 1) acc += w2 * xz[(size_t)(t-1) * (2*ED_) + e];
  acc += w3 * xz[(size_t)t * (2*ED_) + e];
  u[(size_t)t * ED_ + e] = silu_f(acc);
}

// ---- chunked selective scan ----
__global__ __launch_bounds__(256) void scan_phase1(
    const float* __restrict__ delta, const float* __restrict__ u,
    const float* __restrict__ xdbl, const float* __restrict__ A_log,
    float* __restrict__ hend, float* __restrict__ Pend)
{
  const int tid = threadIdx.x;
  const int n = tid & 31;
  const int e = blockIdx.x * 8 + (tid >> 5);
  const int c = blockIdx.y;
  const float a = -expf(A_log[e * NST + n]);
  float h = 0.f, P = 1.f;
  const int t0 = c * CHUNK;
  #pragma unroll 4
  for (int t = t0; t < t0 + CHUNK; ++t) {
    const float sd = delta[(size_t)t * ED_ + e];
    const float uv = u[(size_t)t * ED_ + e];
    const float Bv = xdbl[(size_t)t * 128 + 64 + n];
    const float dA = __expf(sd * a);
    h = fmaf(dA, h, sd * uv * Bv);
    P *= dA;
  }
  const int idx = c * (ED_ * NST) + blockIdx.x * 256 + tid;
  hend[idx] = h;
  Pend[idx] = P;
}

__global__ __launch_bounds__(256) void scan_phase2(
    const float* __restrict__ hend, float* __restrict__ Pend_hin)
{
  const int idx = blockIdx.x * 256 + threadIdx.x;
  float hc = 0.f;
  #pragma unroll
  for (int c = 0; c < NCH; ++c) {
    const int off = c * (ED_ * NST) + idx;
    const float P = Pend_hin[off];
    const float hn = hend[off];
    Pend_hin[off] = hc;
    hc = fmaf(P, hc, hn);
  }
}

// phase 3: re-scan from true h_in; writes y as bf16 (feeds MFMA out-GEMM)
__global__ __launch_bounds__(256) void scan_phase3(
    const float* __restrict__ delta, const float* __restrict__ u,
    const float* __restrict__ xdbl, const float* __restrict__ A_log,
    const float* __restrict__ hin, const float* __restrict__ Dp,
    const float* __restrict__ xz, __bf16* __restrict__ y)
{
  const int tid = threadIdx.x;
  const int n = tid & 31;
  const int e = blockIdx.x * 8 + (tid >> 5);
  const int c = blockIdx.y;
  const float a = -expf(A_log[e * NST + n]);
  const float dp = Dp[e];
  float h = hin[c * (ED_ * NST) + blockIdx.x * 256 + tid];
  const int t0 = c * CHUNK;
  #pragma unroll 2
  for (int t = t0; t < t0 + CHUNK; ++t) {
    const float sd = delta[(size_t)t * ED_ + e];
    const float uv = u[(size_t)t * ED_ + e];
    const float Bv = xdbl[(size_t)t * 128 + 64 + n];
    const float Cv = xdbl[(size_t)t * 128 + 96 + n];
    const float dA = __expf(sd * a);
    h = fmaf(dA, h, sd * uv * Bv);
    float p = h * Cv;
    #pragma unroll
    for (int off = 16; off; off >>= 1) p += __shfl_xor(p, off, 64);
    if (n == 0) {
      const float zv = xz[(size_t)t * (2*ED_) + ED_ + e];
      y[(size_t)t * ED_ + e] = (__bf16)((p + uv * dp) * silu_f(zv));
    }
  }
}

__global__ __launch_bounds__(256) void colmean_k(const float* __restrict__ hf, float* __restrict__ cm)
{
  const int d = blockIdx.x * 256 + threadIdx.x;
  float s = 0.f;
  for (int t = 0; t < L_; ++t) s += hf[(size_t)t * D_ + d];
  cm[d] = s * (1.f / L_);
}

__global__ __launch_bounds__(256) void state_k(
    const float* __restrict__ cm, const float* __restrict__ spw,
    const float* __restrict__ spb, float* __restrict__ out)
{
  __shared__ float red[4];
  const int nidx = blockIdx.x;
  const int tid = threadIdx.x;
  float s = 0.f;
  for (int d = tid; d < D_; d += 256) s += cm[d] * spw[(size_t)nidx * D_ + d];
  #pragma unroll
  for (int off = 32; off; off >>= 1) s += __shfl_down(s, off, 64);
  if ((tid & 63) == 0) red[tid >> 6] = s;
  __syncthreads();
  if (tid == 0) out[nidx] = red[0] + red[1] + red[2] + red[3] + spb[nidx];
}

extern "C" void kernel_launch(void* const* d_in, const int* in_sizes, int n_in,
                              void* d_out, int out_size, void* d_ws, size_t ws_size,
                              hipStream_t stream) {
  const float* x        = (const float*)d_in[0];
  const float* Wi       = (const float*)d_in[1];
  const float* bi       = (const float*)d_in[2];
  const float* ln_g     = (const float*)d_in[3];
  const float* ln_b     = (const float*)d_in[4];
  const float* in_w     = (const float*)d_in[5];
  const float* conv_w   = (const float*)d_in[6];
  const float* conv_b   = (const float*)d_in[7];
  const float* xproj_w  = (const float*)d_in[8];
  const float* dtproj_w = (const float*)d_in[9];
  const float* dtproj_b = (const float*)d_in[10];
  const float* A_log    = (const float*)d_in[11];
  const float* Dp       = (const float*)d_in[12];
  const float* out_w    = (const float*)d_in[13];
  const float* fn_g     = (const float*)d_in[14];
  const float* fn_b     = (const float*)d_in[15];
  const float* sp_w     = (const float*)d_in[16];
  const float* sp_b     = (const float*)d_in[17];
  float* out  = (float*)d_out;
  float* ws_f = (float*)d_ws;

  float* h_buf  = ws_f;                // 1048576
  float* xz     = ws_f + 1048576;      // 4194304
  float* u_buf  = ws_f + 5242880;      // 2097152
  float* xdbl   = ws_f + 7340032;      // 131072
  float* delta  = ws_f + 7471104;      // 2097152
  float* hend   = ws_f + 9568256;      // 524288
  float* pend   = ws_f + 10092544;     // 524288
  float* cmean  = ws_f + 10616832;     // 1024
  __bf16* nbf   = (__bf16*)(ws_f + 10617856);  // 1M bf16 (normed / x)
  __bf16* ybf   = (__bf16*)(ws_f + 11142144);  // 2M bf16 (y)
  __bf16* wbf   = (__bf16*)(ws_f + 12190720);  // 4.19M bf16 (weights)
  // split-K partials: overlays hend+pend (1M floats, dead until scan_phase1)
  float* skpart = hend;                // KSPL * 1024 * 128 = 1048576

  const dim3 blk(256);

  // h = x @ Wi^T + bi   (bf16 MFMA)
  f2bf_k<<<512, blk, 0, stream>>>(x, nbf, L_ * D_);
  f2bf_k<<<512, blk, 0, stream>>>(Wi, wbf, D_ * D_);
  gemm_mfma<<<dim3(D_/128, L_/128), blk, 0, stream>>>(nbf, wbf, bi, h_buf, D_, D_, 4);

  for (int i = 0; i < NB_; ++i) {
    layernorm_bf_k<<<L_, blk, 0, stream>>>(h_buf, ln_g + i*D_, ln_b + i*D_, nbf);
    // xz = normed @ in_w^T
    f2bf_k<<<2048, blk, 0, stream>>>(in_w + (size_t)i*2*ED_*D_, wbf, 2*ED_*D_);
    gemm_mfma<<<dim3(2*ED_/128, L_/128), blk, 0, stream>>>(nbf, wbf, nullptr, xz, 2*ED_, D_, 0);
    conv_silu_k<<<dim3(ED_/256, L_), blk, 0, stream>>>(
        xz, conv_w + (size_t)i*ED_*KCONV, conv_b + (size_t)i*ED_, u_buf);
    // x_dbl = u @ xproj^T  (fp32 split-K over 8 chunks)
    gemm_bt_sk<<<dim3(128/64, L_/64, KSPL), blk, 0, stream>>>(
        u_buf, ED_, xproj_w + (size_t)i*128*ED_, ED_, skpart, 128, L_, 128, ED_);
    sk_reduce_k<<<dim3(L_*128/4/256), blk, 0, stream>>>(skpart, xdbl, L_ * 128);
    // delta = softplus(dt @ dtproj^T + b)  (fp32, K=64)
    gemm_bt<<<dim3(ED_/64, L_/64), blk, 0, stream>>>(
        xdbl, 128, dtproj_w + (size_t)i*ED_*DTR_, DTR_, dtproj_b + (size_t)i*ED_,
        delta, ED_, L_, ED_, DTR_, 4 | 2);
    // chunked scan
    scan_phase1<<<dim3(ED_/8, NCH), blk, 0, stream>>>(
        delta, u_buf, xdbl, A_log + (size_t)i*ED_*NST, hend, pend);
    scan_phase2<<<dim3(ED_*NST/256), blk, 0, stream>>>(hend, pend);
    scan_phase3<<<dim3(ED_/8, NCH), blk, 0, stream>>>(
        delta, u_buf, xdbl, A_log + (size_t)i*ED_*NST, pend,
        Dp + (size_t)i*ED_, xz, ybf);
    // h += y @ out_w^T   (bf16 MFMA accumulate)
    f2bf_k<<<1024, blk, 0, stream>>>(out_w + (size_t)i*D_*ED_, wbf, D_*ED_);
    gemm_mfma<<<dim3(D_/128, L_/128), blk, 0, stream>>>(ybf, wbf, nullptr, h_buf, D_, ED_, 1);
  }

  layernorm_k<<<L_, blk, 0, stream>>>(h_buf, fn_g, fn_b, out);
  colmean_k<<<D_/256, blk, 0, stream>>>(out, cmean);
  state_k<<<NST, blk, 0, stream>>>(cmean, sp_w, sp_b, out + (size_t)L_*D_);
}

// Round 5
// 965.254 us; speedup vs baseline: 5.6984x; 1.3007x over previous
//
#include <hip/hip_runtime.h>
#include <math.h>

#define D_    1024
#define ED_   2048
#define NST   32
#define KCONV 4
#define DTR_  64
#define L_    1024
#define NB_   4
#define NCH   8
#define CHUNK (L_ / NCH)
#define KSPL  8

typedef __bf16 bf16_8 __attribute__((ext_vector_type(8)));
typedef __bf16 bf16_4 __attribute__((ext_vector_type(4)));
typedef float  f32x4  __attribute__((ext_vector_type(4)));

__device__ __forceinline__ float softplus_f(float x) {
  return x > 20.f ? x : log1pf(expf(x));
}
__device__ __forceinline__ float silu_f(float x) {
  return x / (1.f + expf(-x));
}

// fp32 -> bf16 (n multiple of 2048)
__global__ __launch_bounds__(256) void f2bf_k(
    const float* __restrict__ in, __bf16* __restrict__ out, int n)
{
  const int i = (blockIdx.x * 256 + threadIdx.x) * 8;
  if (i >= n) return;
  const float4 a = *reinterpret_cast<const float4*>(in + i);
  const float4 b = *reinterpret_cast<const float4*>(in + i + 4);
  bf16_8 v;
  v[0]=(__bf16)a.x; v[1]=(__bf16)a.y; v[2]=(__bf16)a.z; v[3]=(__bf16)a.w;
  v[4]=(__bf16)b.x; v[5]=(__bf16)b.y; v[6]=(__bf16)b.z; v[7]=(__bf16)b.w;
  *reinterpret_cast<bf16_8*>(out + i) = v;
}

// ---- MFMA bf16 GEMM: C[M,N] = A[M,K] @ W[N,K]^T ----
// 128x128 tile, BK=32, 4 waves, each wave 64x64 (4x4 frags of 16x16x32)
// flags: 1=accumulate into C, 4=bias
__global__ __launch_bounds__(256) void gemm_mfma(
    const __bf16* __restrict__ A, const __bf16* __restrict__ W,
    const float* __restrict__ bias, float* __restrict__ C, int ldc,
    int K, int flags)
{
  __shared__ __bf16 As[128 * 32];
  __shared__ __bf16 Ws[128 * 32];
  const int tid  = threadIdx.x;
  const int lane = tid & 63;
  const int w    = tid >> 6;
  const int wr   = w >> 1, wc = w & 1;
  const int row0 = blockIdx.y * 128, col0 = blockIdx.x * 128;

  f32x4 acc[4][4] = {};

  for (int k0 = 0; k0 < K; k0 += 32) {
    #pragma unroll
    for (int j = 0; j < 2; ++j) {
      const int inst = w * 2 + j;           // 0..7, wave-uniform
      const int eo   = inst * 512 + lane * 8;
      const int r    = eo >> 5, k = eo & 31;
      __builtin_amdgcn_global_load_lds(
          (const __attribute__((address_space(1))) void*)(A + (size_t)(row0 + r) * K + k0 + k),
          (__attribute__((address_space(3))) void*)(&As[inst * 512]), 16, 0, 0);
      __builtin_amdgcn_global_load_lds(
          (const __attribute__((address_space(1))) void*)(W + (size_t)(col0 + r) * K + k0 + k),
          (__attribute__((address_space(3))) void*)(&Ws[inst * 512]), 16, 0, 0);
    }
    __syncthreads();
    bf16_8 af[4], bfr[4];
    const int kk  = (lane >> 4) * 8;
    const int r16 = lane & 15;
    #pragma unroll
    for (int m = 0; m < 4; ++m)
      af[m] = *reinterpret_cast<const bf16_8*>(&As[(wr * 64 + m * 16 + r16) * 32 + kk]);
    #pragma unroll
    for (int n = 0; n < 4; ++n)
      bfr[n] = *reinterpret_cast<const bf16_8*>(&Ws[(wc * 64 + n * 16 + r16) * 32 + kk]);
    #pragma unroll
    for (int m = 0; m < 4; ++m)
      #pragma unroll
      for (int n = 0; n < 4; ++n)
        acc[m][n] = __builtin_amdgcn_mfma_f32_16x16x32_bf16(af[m], bfr[n], acc[m][n], 0, 0, 0);
    __syncthreads();
  }

  const int crow = (lane >> 4) * 4;
  const int ccol = lane & 15;
  #pragma unroll
  for (int m = 0; m < 4; ++m)
    #pragma unroll
    for (int n = 0; n < 4; ++n) {
      const int col = col0 + wc * 64 + n * 16 + ccol;
      const float bv = (flags & 4) ? bias[col] : 0.f;
      #pragma unroll
      for (int r = 0; r < 4; ++r) {
        const int row = row0 + wr * 64 + m * 16 + crow + r;
        float* cp = C + (size_t)row * ldc + col;
        float v = acc[m][n][r] + bv;
        if (flags & 1) v += *cp;
        *cp = v;
      }
    }
}

// fp32 GEMM: C[M,N] = A @ W^T  flags: 1=acc, 2=softplus, 4=bias
__global__ __launch_bounds__(256) void gemm_bt(
    const float* __restrict__ A, int lda,
    const float* __restrict__ W, int ldw,
    const float* __restrict__ bias,
    float* __restrict__ C, int ldc,
    int M, int N, int K, int flags)
{
  __shared__ float As[16][65];
  __shared__ float Ws[16][65];
  const int tid = threadIdx.x;
  const int row0 = blockIdx.y * 64, col0 = blockIdx.x * 64;
  const int tx = tid & 15, ty = tid >> 4;
  const int lm = tid >> 2, lk = (tid & 3) << 2;
  float acc[4][4] = {};
  for (int k0 = 0; k0 < K; k0 += 16) {
    float4 av = make_float4(0.f,0.f,0.f,0.f), wv = make_float4(0.f,0.f,0.f,0.f);
    if (row0 + lm < M && k0 + lk + 3 < K)
      av = *reinterpret_cast<const float4*>(A + (size_t)(row0 + lm) * lda + k0 + lk);
    if (col0 + lm < N && k0 + lk + 3 < K)
      wv = *reinterpret_cast<const float4*>(W + (size_t)(col0 + lm) * ldw + k0 + lk);
    __syncthreads();
    As[lk+0][lm]=av.x; As[lk+1][lm]=av.y; As[lk+2][lm]=av.z; As[lk+3][lm]=av.w;
    Ws[lk+0][lm]=wv.x; Ws[lk+1][lm]=wv.y; Ws[lk+2][lm]=wv.z; Ws[lk+3][lm]=wv.w;
    __syncthreads();
    #pragma unroll
    for (int k = 0; k < 16; ++k) {
      float a0 = As[k][ty*4+0], a1 = As[k][ty*4+1], a2 = As[k][ty*4+2], a3 = As[k][ty*4+3];
      float b0 = Ws[k][tx*4+0], b1 = Ws[k][tx*4+1], b2 = Ws[k][tx*4+2], b3 = Ws[k][tx*4+3];
      acc[0][0] += a0*b0; acc[0][1] += a0*b1; acc[0][2] += a0*b2; acc[0][3] += a0*b3;
      acc[1][0] += a1*b0; acc[1][1] += a1*b1; acc[1][2] += a1*b2; acc[1][3] += a1*b3;
      acc[2][0] += a2*b0; acc[2][1] += a2*b1; acc[2][2] += a2*b2; acc[2][3] += a2*b3;
      acc[3][0] += a3*b0; acc[3][1] += a3*b1; acc[3][2] += a3*b2; acc[3][3] += a3*b3;
    }
  }
  #pragma unroll
  for (int i = 0; i < 4; ++i) {
    int r = row0 + ty*4 + i;
    if (r >= M) continue;
    int c = col0 + tx*4;
    if (c >= N) continue;
    float4 v = make_float4(acc[i][0], acc[i][1], acc[i][2], acc[i][3]);
    if (flags & 4) {
      const float4 bv = *reinterpret_cast<const float4*>(bias + c);
      v.x += bv.x; v.y += bv.y; v.z += bv.z; v.w += bv.w;
    }
    if (flags & 2) { v.x=softplus_f(v.x); v.y=softplus_f(v.y); v.z=softplus_f(v.z); v.w=softplus_f(v.w); }
    float* cp = C + (size_t)r * ldc + c;
    if (flags & 1) {
      float4 ov = *reinterpret_cast<const float4*>(cp);
      v.x += ov.x; v.y += ov.y; v.z += ov.z; v.w += ov.w;
    }
    *reinterpret_cast<float4*>(cp) = v;
  }
}

// split-K fp32 GEMM: partials[z][M][N] = A[:, z*Kc:(z+1)*Kc] @ W^T chunk
__global__ __launch_bounds__(256) void gemm_bt_sk(
    const float* __restrict__ A, int lda,
    const float* __restrict__ W, int ldw,
    float* __restrict__ partials, int ldc,
    int M, int N, int K)
{
  __shared__ float As[16][65];
  __shared__ float Ws[16][65];
  const int tid = threadIdx.x;
  const int row0 = blockIdx.y * 64, col0 = blockIdx.x * 64;
  const int Kc = K / KSPL;
  const int kbase = blockIdx.z * Kc;
  const int tx = tid & 15, ty = tid >> 4;
  const int lm = tid >> 2, lk = (tid & 3) << 2;
  float acc[4][4] = {};
  for (int k0 = kbase; k0 < kbase + Kc; k0 += 16) {
    float4 av = *reinterpret_cast<const float4*>(A + (size_t)(row0 + lm) * lda + k0 + lk);
    float4 wv = *reinterpret_cast<const float4*>(W + (size_t)(col0 + lm) * ldw + k0 + lk);
    __syncthreads();
    As[lk+0][lm]=av.x; As[lk+1][lm]=av.y; As[lk+2][lm]=av.z; As[lk+3][lm]=av.w;
    Ws[lk+0][lm]=wv.x; Ws[lk+1][lm]=wv.y; Ws[lk+2][lm]=wv.z; Ws[lk+3][lm]=wv.w;
    __syncthreads();
    #pragma unroll
    for (int k = 0; k < 16; ++k) {
      float a0 = As[k][ty*4+0], a1 = As[k][ty*4+1], a2 = As[k][ty*4+2], a3 = As[k][ty*4+3];
      float b0 = Ws[k][tx*4+0], b1 = Ws[k][tx*4+1], b2 = Ws[k][tx*4+2], b3 = Ws[k][tx*4+3];
      acc[0][0] += a0*b0; acc[0][1] += a0*b1; acc[0][2] += a0*b2; acc[0][3] += a0*b3;
      acc[1][0] += a1*b0; acc[1][1] += a1*b1; acc[1][2] += a1*b2; acc[1][3] += a1*b3;
      acc[2][0] += a2*b0; acc[2][1] += a2*b1; acc[2][2] += a2*b2; acc[2][3] += a2*b3;
      acc[3][0] += a3*b0; acc[3][1] += a3*b1; acc[3][2] += a3*b2; acc[3][3] += a3*b3;
    }
  }
  float* base = partials + (size_t)blockIdx.z * M * ldc;
  #pragma unroll
  for (int i = 0; i < 4; ++i) {
    const int r = row0 + ty*4 + i;
    float4 v = make_float4(acc[i][0], acc[i][1], acc[i][2], acc[i][3]);
    *reinterpret_cast<float4*>(base + (size_t)r * ldc + col0 + tx*4) = v;
  }
}

// reduce KSPL partials -> C  (elements = M*N)
__global__ __launch_bounds__(256) void sk_reduce_k(
    const float* __restrict__ partials, float* __restrict__ C, int elems)
{
  const int i = (blockIdx.x * 256 + threadIdx.x) * 4;
  if (i >= elems) return;
  float4 s = *reinterpret_cast<const float4*>(partials + i);
  #pragma unroll
  for (int z = 1; z < KSPL; ++z) {
    const float4 p = *reinterpret_cast<const float4*>(partials + (size_t)z * elems + i);
    s.x += p.x; s.y += p.y; s.z += p.z; s.w += p.w;
  }
  *reinterpret_cast<float4*>(C + i) = s;
}

// layernorm, fp32 out (final LN)
__global__ __launch_bounds__(256) void layernorm_k(
    const float* __restrict__ x, const float* __restrict__ g,
    const float* __restrict__ b, float* __restrict__ out)
{
  __shared__ float red[8];
  const int row = blockIdx.x;
  const int tid = threadIdx.x;
  const float* xr = x + (size_t)row * D_;
  float4 v = *reinterpret_cast<const float4*>(xr + tid * 4);
  float s = v.x + v.y + v.z + v.w;
  #pragma unroll
  for (int off = 32; off; off >>= 1) s += __shfl_down(s, off, 64);
  if ((tid & 63) == 0) red[tid >> 6] = s;
  __syncthreads();
  const float m = (red[0] + red[1] + red[2] + red[3]) * (1.f / D_);
  float dx0 = v.x - m, dx1 = v.y - m, dx2 = v.z - m, dx3 = v.w - m;
  float ss = dx0*dx0 + dx1*dx1 + dx2*dx2 + dx3*dx3;
  #pragma unroll
  for (int off = 32; off; off >>= 1) ss += __shfl_down(ss, off, 64);
  if ((tid & 63) == 0) red[4 + (tid >> 6)] = ss;
  __syncthreads();
  const float var = (red[4] + red[5] + red[6] + red[7]) * (1.f / D_);
  const float rs = rsqrtf(var + 1e-5f);
  const int c = tid * 4;
  const float4 gv = *reinterpret_cast<const float4*>(g + c);
  const float4 bv = *reinterpret_cast<const float4*>(b + c);
  float4 o;
  o.x = dx0 * rs * gv.x + bv.x;
  o.y = dx1 * rs * gv.y + bv.y;
  o.z = dx2 * rs * gv.z + bv.z;
  o.w = dx3 * rs * gv.w + bv.w;
  *reinterpret_cast<float4*>(out + (size_t)row * D_ + c) = o;
}

// layernorm with bf16 out (feeds MFMA GEMM)
__global__ __launch_bounds__(256) void layernorm_bf_k(
    const float* __restrict__ x, const float* __restrict__ g,
    const float* __restrict__ b, __bf16* __restrict__ out)
{
  __shared__ float red[8];
  const int row = blockIdx.x;
  const int tid = threadIdx.x;
  const float* xr = x + (size_t)row * D_;
  float4 v = *reinterpret_cast<const float4*>(xr + tid * 4);
  float s = v.x + v.y + v.z + v.w;
  #pragma unroll
  for (int off = 32; off; off >>= 1) s += __shfl_down(s, off, 64);
  if ((tid & 63) == 0) red[tid >> 6] = s;
  __syncthreads();
  const float m = (red[0] + red[1] + red[2] + red[3]) * (1.f / D_);
  float dx0 = v.x - m, dx1 = v.y - m, dx2 = v.z - m, dx3 = v.w - m;
  float ss = dx0*dx0 + dx1*dx1 + dx2*dx2 + dx3*dx3;
  #pragma unroll
  for (int off = 32; off; off >>= 1) ss += __shfl_down(ss, off, 64);
  if ((tid & 63) == 0) red[4 + (tid >> 6)] = ss;
  __syncthreads();
  const float var = (red[4] + red[5] + red[6] + red[7]) * (1.f / D_);
  const float rs = rsqrtf(var + 1e-5f);
  const int c = tid * 4;
  const float4 gv = *reinterpret_cast<const float4*>(g + c);
  const float4 bv = *reinterpret_cast<const float4*>(b + c);
  bf16_4 o;
  o[0] = (__bf16)(dx0 * rs * gv.x + bv.x);
  o[1] = (__bf16)(dx1 * rs * gv.y + bv.y);
  o[2] = (__bf16)(dx2 * rs * gv.z + bv.z);
  o[3] = (__bf16)(dx3 * rs * gv.w + bv.w);
  *reinterpret_cast<bf16_4*>(out + (size_t)row * D_ + c) = o;
}

// depthwise causal conv K=4 + bias + silu
__global__ __launch_bounds__(256) void conv_silu_k(
    const float* __restrict__ xz, const float* __restrict__ cw,
    const float* __restrict__ cb, float* __restrict__ u)
{
  const int e = blockIdx.x * 256 + threadIdx.x;
  const int t = blockIdx.y;
  const float w0 = cw[e*4+0], w1 = cw[e*4+1], w2 = cw[e*4+2], w3 = cw[e*4+3];
  float acc = cb[e];
  if (t >= 3) acc += w0 * xz[(size_t)(t-3) * (2*ED_) + e];
  if (t >= 2) acc += w1 * xz[(size_t)(t-2) * (2*ED_) + e];
  if (t >= 1) acc += w2 * xz[(size_t)(t-1) * (2*ED_) + e];
  acc += w3 * xz[(size_t)t * (2*ED_) + e];
  u[(size_t)t * ED_ + e] = silu_f(acc);
}

// ---- chunked selective scan ----
// phase 1: per-chunk local scan from h=0; P via separable sum (P=exp(a*sum(sd)))
__global__ __launch_bounds__(256) void scan_phase1(
    const float* __restrict__ delta, const float* __restrict__ u,
    const float* __restrict__ xdbl, const float* __restrict__ A_log,
    float* __restrict__ hend, float* __restrict__ Pend)
{
  const int tid = threadIdx.x;
  const int n = tid & 31;
  const int e = blockIdx.x * 8 + (tid >> 5);
  const int c = blockIdx.y;
  const float a = -expf(A_log[e * NST + n]);
  float h = 0.f, S = 0.f;
  const int t0 = c * CHUNK;
  #pragma unroll 8
  for (int t = t0; t < t0 + CHUNK; ++t) {
    const float sd = delta[(size_t)t * ED_ + e];
    const float uv = u[(size_t)t * ED_ + e];
    const float Bv = xdbl[(size_t)t * 128 + 64 + n];
    const float dA = __expf(sd * a);
    h = fmaf(dA, h, sd * uv * Bv);
    S += sd;
  }
  const int idx = c * (ED_ * NST) + blockIdx.x * 256 + tid;
  hend[idx] = h;
  Pend[idx] = __expf(a * S);
}

__global__ __launch_bounds__(256) void scan_phase2(
    const float* __restrict__ hend, float* __restrict__ Pend_hin)
{
  const int idx = blockIdx.x * 256 + threadIdx.x;
  float hc = 0.f;
  #pragma unroll
  for (int c = 0; c < NCH; ++c) {
    const int off = c * (ED_ * NST) + idx;
    const float P = Pend_hin[off];
    const float hn = hend[off];
    Pend_hin[off] = hc;
    hc = fmaf(P, hc, hn);
  }
}

// phase 3: re-scan from true h_in; LDS-transpose deferred n-reduction.
// Each lane writes p=h*C to p_lds[c][t%32][n]; every 32 steps lane n sums
// row n (conflict-free: bank=(n+k)%32) and emits y for its own timestep.
__global__ __launch_bounds__(256, 4) void scan_phase3(
    const float* __restrict__ delta, const float* __restrict__ u,
    const float* __restrict__ xdbl, const float* __restrict__ A_log,
    const float* __restrict__ hin, const float* __restrict__ Dp,
    const float* __restrict__ xz, __bf16* __restrict__ y)
{
  __shared__ float p_lds[8][32][33];
  const int tid = threadIdx.x;
  const int n = tid & 31;
  const int c = tid >> 5;
  const int e = blockIdx.x * 8 + c;
  const int ch = blockIdx.y;
  const float a = -expf(A_log[e * NST + n]);
  const float dp = Dp[e];
  float h = hin[ch * (ED_ * NST) + blockIdx.x * 256 + tid];
  const int t0 = ch * CHUNK;
  for (int tb = 0; tb < CHUNK; tb += 32) {
    #pragma unroll 8
    for (int j = 0; j < 32; ++j) {
      const int t = t0 + tb + j;
      const float sd = delta[(size_t)t * ED_ + e];
      const float uv = u[(size_t)t * ED_ + e];
      const float Bv = xdbl[(size_t)t * 128 + 64 + n];
      const float Cv = xdbl[(size_t)t * 128 + 96 + n];
      const float dA = __expf(sd * a);
      h = fmaf(dA, h, sd * uv * Bv);
      p_lds[c][j][n] = h * Cv;
    }
    __syncthreads();
    float s = 0.f;
    #pragma unroll
    for (int k = 0; k < 32; ++k) s += p_lds[c][n][k];
    const int t = t0 + tb + n;
    const float uvt = u[(size_t)t * ED_ + e];
    const float zv = xz[(size_t)t * (2*ED_) + ED_ + e];
    y[(size_t)t * ED_ + e] = (__bf16)((s + uvt * dp) * silu_f(zv));
    __syncthreads();
  }
}

__global__ __launch_bounds__(256) void colmean_k(const float* __restrict__ hf, float* __restrict__ cm)
{
  const int d = blockIdx.x * 256 + threadIdx.x;
  float s = 0.f;
  for (int t = 0; t < L_; ++t) s += hf[(size_t)t * D_ + d];
  cm[d] = s * (1.f / L_);
}

__global__ __launch_bounds__(256) void state_k(
    const float* __restrict__ cm, const float* __restrict__ spw,
    const float* __restrict__ spb, float* __restrict__ out)
{
  __shared__ float red[4];
  const int nidx = blockIdx.x;
  const int tid = threadIdx.x;
  float s = 0.f;
  for (int d = tid; d < D_; d += 256) s += cm[d] * spw[(size_t)nidx * D_ + d];
  #pragma unroll
  for (int off = 32; off; off >>= 1) s += __shfl_down(s, off, 64);
  if ((tid & 63) == 0) red[tid >> 6] = s;
  __syncthreads();
  if (tid == 0) out[nidx] = red[0] + red[1] + red[2] + red[3] + spb[nidx];
}

extern "C" void kernel_launch(void* const* d_in, const int* in_sizes, int n_in,
                              void* d_out, int out_size, void* d_ws, size_t ws_size,
                              hipStream_t stream) {
  const float* x        = (const float*)d_in[0];
  const float* Wi       = (const float*)d_in[1];
  const float* bi       = (const float*)d_in[2];
  const float* ln_g     = (const float*)d_in[3];
  const float* ln_b     = (const float*)d_in[4];
  const float* in_w     = (const float*)d_in[5];
  const float* conv_w   = (const float*)d_in[6];
  const float* conv_b   = (const float*)d_in[7];
  const float* xproj_w  = (const float*)d_in[8];
  const float* dtproj_w = (const float*)d_in[9];
  const float* dtproj_b = (const float*)d_in[10];
  const float* A_log    = (const float*)d_in[11];
  const float* Dp       = (const float*)d_in[12];
  const float* out_w    = (const float*)d_in[13];
  const float* fn_g     = (const float*)d_in[14];
  const float* fn_b     = (const float*)d_in[15];
  const float* sp_w     = (const float*)d_in[16];
  const float* sp_b     = (const float*)d_in[17];
  float* out  = (float*)d_out;
  float* ws_f = (float*)d_ws;

  float* h_buf  = ws_f;                // 1048576
  float* xz     = ws_f + 1048576;      // 4194304
  float* u_buf  = ws_f + 5242880;      // 2097152
  float* xdbl   = ws_f + 7340032;      // 131072
  float* delta  = ws_f + 7471104;      // 2097152
  float* hend   = ws_f + 9568256;      // 524288
  float* pend   = ws_f + 10092544;     // 524288
  float* cmean  = ws_f + 10616832;     // 1024
  __bf16* nbf   = (__bf16*)(ws_f + 10617856);  // 1M bf16 (normed / x)
  __bf16* ybf   = (__bf16*)(ws_f + 11142144);  // 2M bf16 (y)
  __bf16* wbf   = (__bf16*)(ws_f + 12190720);  // 4.19M bf16 (weights)
  // split-K partials: overlays hend+pend (1M floats, dead until scan_phase1)
  float* skpart = hend;                // KSPL * 1024 * 128 = 1048576

  const dim3 blk(256);

  // h = x @ Wi^T + bi   (bf16 MFMA)
  f2bf_k<<<512, blk, 0, stream>>>(x, nbf, L_ * D_);
  f2bf_k<<<512, blk, 0, stream>>>(Wi, wbf, D_ * D_);
  gemm_mfma<<<dim3(D_/128, L_/128), blk, 0, stream>>>(nbf, wbf, bi, h_buf, D_, D_, 4);

  for (int i = 0; i < NB_; ++i) {
    layernorm_bf_k<<<L_, blk, 0, stream>>>(h_buf, ln_g + i*D_, ln_b + i*D_, nbf);
    // xz = normed @ in_w^T
    f2bf_k<<<2048, blk, 0, stream>>>(in_w + (size_t)i*2*ED_*D_, wbf, 2*ED_*D_);
    gemm_mfma<<<dim3(2*ED_/128, L_/128), blk, 0, stream>>>(nbf, wbf, nullptr, xz, 2*ED_, D_, 0);
    conv_silu_k<<<dim3(ED_/256, L_), blk, 0, stream>>>(
        xz, conv_w + (size_t)i*ED_*KCONV, conv_b + (size_t)i*ED_, u_buf);
    // x_dbl = u @ xproj^T  (fp32 split-K over 8 chunks)
    gemm_bt_sk<<<dim3(128/64, L_/64, KSPL), blk, 0, stream>>>(
        u_buf, ED_, xproj_w + (size_t)i*128*ED_, ED_, skpart, 128, L_, 128, ED_);
    sk_reduce_k<<<dim3(L_*128/4/256), blk, 0, stream>>>(skpart, xdbl, L_ * 128);
    // delta = softplus(dt @ dtproj^T + b)  (fp32, K=64)
    gemm_bt<<<dim3(ED_/64, L_/64), blk, 0, stream>>>(
        xdbl, 128, dtproj_w + (size_t)i*ED_*DTR_, DTR_, dtproj_b + (size_t)i*ED_,
        delta, ED_, L_, ED_, DTR_, 4 | 2);
    // chunked scan
    scan_phase1<<<dim3(ED_/8, NCH), blk, 0, stream>>>(
        delta, u_buf, xdbl, A_log + (size_t)i*ED_*NST, hend, pend);
    scan_phase2<<<dim3(ED_*NST/256), blk, 0, stream>>>(hend, pend);
    scan_phase3<<<dim3(ED_/8, NCH), blk, 0, stream>>>(
        delta, u_buf, xdbl, A_log + (size_t)i*ED_*NST, pend,
        Dp + (size_t)i*ED_, xz, ybf);
    // h += y @ out_w^T   (bf16 MFMA accumulate)
    f2bf_k<<<1024, blk, 0, stream>>>(out_w + (size_t)i*D_*ED_, wbf, D_*ED_);
    gemm_mfma<<<dim3(D_/128, L_/128), blk, 0, stream>>>(ybf, wbf, nullptr, h_buf, D_, ED_, 1);
  }

  layernorm_k<<<L_, blk, 0, stream>>>(h_buf, fn_g, fn_b, out);
  colmean_k<<<D_/256, blk, 0, stream>>>(out, cmean);
  state_k<<<NST, blk, 0, stream>>>(cmean, sp_w, sp_b, out + (size_t)L_*D_);
}

// Round 6
// 811.418 us; speedup vs baseline: 6.7787x; 1.1896x over previous
//
#include <hip/hip_runtime.h>
#include <math.h>

#define D_    1024
#define ED_   2048
#define NST   32
#define KCONV 4
#define DTR_  64
#define L_    1024
#define NB_   4
#define NCH   8
#define CHUNK (L_ / NCH)
#define KSPL  8
#define ZSPL  4

typedef __bf16 bf16_8 __attribute__((ext_vector_type(8)));
typedef __bf16 bf16_4 __attribute__((ext_vector_type(4)));
typedef float  f32x4  __attribute__((ext_vector_type(4)));

__device__ __forceinline__ float softplus_f(float x) {
  return x > 20.f ? x : log1pf(expf(x));
}
__device__ __forceinline__ float silu_f(float x) {
  return x / (1.f + expf(-x));
}

// fp32 -> bf16 (n multiple of 2048)
__global__ __launch_bounds__(256) void f2bf_k(
    const float* __restrict__ in, __bf16* __restrict__ out, int n)
{
  const int i = (blockIdx.x * 256 + threadIdx.x) * 8;
  if (i >= n) return;
  const float4 a = *reinterpret_cast<const float4*>(in + i);
  const float4 b = *reinterpret_cast<const float4*>(in + i + 4);
  bf16_8 v;
  v[0]=(__bf16)a.x; v[1]=(__bf16)a.y; v[2]=(__bf16)a.z; v[3]=(__bf16)a.w;
  v[4]=(__bf16)b.x; v[5]=(__bf16)b.y; v[6]=(__bf16)b.z; v[7]=(__bf16)b.w;
  *reinterpret_cast<bf16_8*>(out + i) = v;
}

// ---- MFMA bf16 GEMM: C[M,N] = A[M,K] @ W[N,K]^T ----
// 128x128 tile, BK=32, 4 waves; flags: 1=accumulate, 4=bias
__global__ __launch_bounds__(256) void gemm_mfma(
    const __bf16* __restrict__ A, const __bf16* __restrict__ W,
    const float* __restrict__ bias, float* __restrict__ C, int ldc,
    int K, int flags)
{
  __shared__ __bf16 As[128 * 32];
  __shared__ __bf16 Ws[128 * 32];
  const int tid  = threadIdx.x;
  const int lane = tid & 63;
  const int w    = tid >> 6;
  const int wr   = w >> 1, wc = w & 1;
  const int row0 = blockIdx.y * 128, col0 = blockIdx.x * 128;

  f32x4 acc[4][4] = {};

  for (int k0 = 0; k0 < K; k0 += 32) {
    #pragma unroll
    for (int j = 0; j < 2; ++j) {
      const int inst = w * 2 + j;
      const int eo   = inst * 512 + lane * 8;
      const int r    = eo >> 5, k = eo & 31;
      __builtin_amdgcn_global_load_lds(
          (const __attribute__((address_space(1))) void*)(A + (size_t)(row0 + r) * K + k0 + k),
          (__attribute__((address_space(3))) void*)(&As[inst * 512]), 16, 0, 0);
      __builtin_amdgcn_global_load_lds(
          (const __attribute__((address_space(1))) void*)(W + (size_t)(col0 + r) * K + k0 + k),
          (__attribute__((address_space(3))) void*)(&Ws[inst * 512]), 16, 0, 0);
    }
    __syncthreads();
    bf16_8 af[4], bfr[4];
    const int kk  = (lane >> 4) * 8;
    const int r16 = lane & 15;
    #pragma unroll
    for (int m = 0; m < 4; ++m)
      af[m] = *reinterpret_cast<const bf16_8*>(&As[(wr * 64 + m * 16 + r16) * 32 + kk]);
    #pragma unroll
    for (int n = 0; n < 4; ++n)
      bfr[n] = *reinterpret_cast<const bf16_8*>(&Ws[(wc * 64 + n * 16 + r16) * 32 + kk]);
    #pragma unroll
    for (int m = 0; m < 4; ++m)
      #pragma unroll
      for (int n = 0; n < 4; ++n)
        acc[m][n] = __builtin_amdgcn_mfma_f32_16x16x32_bf16(af[m], bfr[n], acc[m][n], 0, 0, 0);
    __syncthreads();
  }

  const int crow = (lane >> 4) * 4;
  const int ccol = lane & 15;
  #pragma unroll
  for (int m = 0; m < 4; ++m)
    #pragma unroll
    for (int n = 0; n < 4; ++n) {
      const int col = col0 + wc * 64 + n * 16 + ccol;
      const float bv = (flags & 4) ? bias[col] : 0.f;
      #pragma unroll
      for (int r = 0; r < 4; ++r) {
        const int row = row0 + wr * 64 + m * 16 + crow + r;
        float* cp = C + (size_t)row * ldc + col;
        float v = acc[m][n][r] + bv;
        if (flags & 1) v += *cp;
        *cp = v;
      }
    }
}

// split-K MFMA GEMM: partials[z][M][N] = A[:, z*Kc:(z+1)*Kc] @ W^T chunk
__global__ __launch_bounds__(256) void gemm_mfma_sk(
    const __bf16* __restrict__ A, const __bf16* __restrict__ W,
    float* __restrict__ partials, int M, int N, int K, int Kc)
{
  __shared__ __bf16 As[128 * 32];
  __shared__ __bf16 Ws[128 * 32];
  const int tid  = threadIdx.x;
  const int lane = tid & 63;
  const int w    = tid >> 6;
  const int wr   = w >> 1, wc = w & 1;
  const int row0 = blockIdx.y * 128, col0 = blockIdx.x * 128;
  const int kbase = blockIdx.z * Kc;

  f32x4 acc[4][4] = {};

  for (int k0 = kbase; k0 < kbase + Kc; k0 += 32) {
    #pragma unroll
    for (int j = 0; j < 2; ++j) {
      const int inst = w * 2 + j;
      const int eo   = inst * 512 + lane * 8;
      const int r    = eo >> 5, k = eo & 31;
      __builtin_amdgcn_global_load_lds(
          (const __attribute__((address_space(1))) void*)(A + (size_t)(row0 + r) * K + k0 + k),
          (__attribute__((address_space(3))) void*)(&As[inst * 512]), 16, 0, 0);
      __builtin_amdgcn_global_load_lds(
          (const __attribute__((address_space(1))) void*)(W + (size_t)(col0 + r) * K + k0 + k),
          (__attribute__((address_space(3))) void*)(&Ws[inst * 512]), 16, 0, 0);
    }
    __syncthreads();
    bf16_8 af[4], bfr[4];
    const int kk  = (lane >> 4) * 8;
    const int r16 = lane & 15;
    #pragma unroll
    for (int m = 0; m < 4; ++m)
      af[m] = *reinterpret_cast<const bf16_8*>(&As[(wr * 64 + m * 16 + r16) * 32 + kk]);
    #pragma unroll
    for (int n = 0; n < 4; ++n)
      bfr[n] = *reinterpret_cast<const bf16_8*>(&Ws[(wc * 64 + n * 16 + r16) * 32 + kk]);
    #pragma unroll
    for (int m = 0; m < 4; ++m)
      #pragma unroll
      for (int n = 0; n < 4; ++n)
        acc[m][n] = __builtin_amdgcn_mfma_f32_16x16x32_bf16(af[m], bfr[n], acc[m][n], 0, 0, 0);
    __syncthreads();
  }

  float* base = partials + (size_t)blockIdx.z * M * N;
  const int crow = (lane >> 4) * 4;
  const int ccol = lane & 15;
  #pragma unroll
  for (int m = 0; m < 4; ++m)
    #pragma unroll
    for (int n = 0; n < 4; ++n) {
      const int col = col0 + wc * 64 + n * 16 + ccol;
      #pragma unroll
      for (int r = 0; r < 4; ++r) {
        const int row = row0 + wr * 64 + m * 16 + crow + r;
        base[(size_t)row * N + col] = acc[m][n][r];
      }
    }
}

// reduce ZSPL partials -> C; flags: 1=accumulate into C, 4=bias (per column)
__global__ __launch_bounds__(256) void mfma_sk_reduce(
    const float* __restrict__ partials, const float* __restrict__ bias,
    float* __restrict__ C, int elems, int ncols, int flags)
{
  const int i = (blockIdx.x * 256 + threadIdx.x) * 4;
  if (i >= elems) return;
  float4 s = *reinterpret_cast<const float4*>(partials + i);
  #pragma unroll
  for (int z = 1; z < ZSPL; ++z) {
    const float4 p = *reinterpret_cast<const float4*>(partials + (size_t)z * elems + i);
    s.x += p.x; s.y += p.y; s.z += p.z; s.w += p.w;
  }
  if (flags & 4) {
    const float4 bv = *reinterpret_cast<const float4*>(bias + (i % ncols));
    s.x += bv.x; s.y += bv.y; s.z += bv.z; s.w += bv.w;
  }
  if (flags & 1) {
    const float4 ov = *reinterpret_cast<const float4*>(C + i);
    s.x += ov.x; s.y += ov.y; s.z += ov.z; s.w += ov.w;
  }
  *reinterpret_cast<float4*>(C + i) = s;
}

// fp32 GEMM: C[M,N] = A @ W^T  flags: 1=acc, 2=softplus, 4=bias
__global__ __launch_bounds__(256) void gemm_bt(
    const float* __restrict__ A, int lda,
    const float* __restrict__ W, int ldw,
    const float* __restrict__ bias,
    float* __restrict__ C, int ldc,
    int M, int N, int K, int flags)
{
  __shared__ float As[16][65];
  __shared__ float Ws[16][65];
  const int tid = threadIdx.x;
  const int row0 = blockIdx.y * 64, col0 = blockIdx.x * 64;
  const int tx = tid & 15, ty = tid >> 4;
  const int lm = tid >> 2, lk = (tid & 3) << 2;
  float acc[4][4] = {};
  for (int k0 = 0; k0 < K; k0 += 16) {
    float4 av = make_float4(0.f,0.f,0.f,0.f), wv = make_float4(0.f,0.f,0.f,0.f);
    if (row0 + lm < M && k0 + lk + 3 < K)
      av = *reinterpret_cast<const float4*>(A + (size_t)(row0 + lm) * lda + k0 + lk);
    if (col0 + lm < N && k0 + lk + 3 < K)
      wv = *reinterpret_cast<const float4*>(W + (size_t)(col0 + lm) * ldw + k0 + lk);
    __syncthreads();
    As[lk+0][lm]=av.x; As[lk+1][lm]=av.y; As[lk+2][lm]=av.z; As[lk+3][lm]=av.w;
    Ws[lk+0][lm]=wv.x; Ws[lk+1][lm]=wv.y; Ws[lk+2][lm]=wv.z; Ws[lk+3][lm]=wv.w;
    __syncthreads();
    #pragma unroll
    for (int k = 0; k < 16; ++k) {
      float a0 = As[k][ty*4+0], a1 = As[k][ty*4+1], a2 = As[k][ty*4+2], a3 = As[k][ty*4+3];
      float b0 = Ws[k][tx*4+0], b1 = Ws[k][tx*4+1], b2 = Ws[k][tx*4+2], b3 = Ws[k][tx*4+3];
      acc[0][0] += a0*b0; acc[0][1] += a0*b1; acc[0][2] += a0*b2; acc[0][3] += a0*b3;
      acc[1][0] += a1*b0; acc[1][1] += a1*b1; acc[1][2] += a1*b2; acc[1][3] += a1*b3;
      acc[2][0] += a2*b0; acc[2][1] += a2*b1; acc[2][2] += a2*b2; acc[2][3] += a2*b3;
      acc[3][0] += a3*b0; acc[3][1] += a3*b1; acc[3][2] += a3*b2; acc[3][3] += a3*b3;
    }
  }
  #pragma unroll
  for (int i = 0; i < 4; ++i) {
    int r = row0 + ty*4 + i;
    if (r >= M) continue;
    int c = col0 + tx*4;
    if (c >= N) continue;
    float4 v = make_float4(acc[i][0], acc[i][1], acc[i][2], acc[i][3]);
    if (flags & 4) {
      const float4 bv = *reinterpret_cast<const float4*>(bias + c);
      v.x += bv.x; v.y += bv.y; v.z += bv.z; v.w += bv.w;
    }
    if (flags & 2) { v.x=softplus_f(v.x); v.y=softplus_f(v.y); v.z=softplus_f(v.z); v.w=softplus_f(v.w); }
    float* cp = C + (size_t)r * ldc + c;
    if (flags & 1) {
      float4 ov = *reinterpret_cast<const float4*>(cp);
      v.x += ov.x; v.y += ov.y; v.z += ov.z; v.w += ov.w;
    }
    *reinterpret_cast<float4*>(cp) = v;
  }
}

// split-K fp32 GEMM (xproj)
__global__ __launch_bounds__(256) void gemm_bt_sk(
    const float* __restrict__ A, int lda,
    const float* __restrict__ W, int ldw,
    float* __restrict__ partials, int ldc,
    int M, int N, int K)
{
  __shared__ float As[16][65];
  __shared__ float Ws[16][65];
  const int tid = threadIdx.x;
  const int row0 = blockIdx.y * 64, col0 = blockIdx.x * 64;
  const int Kc = K / KSPL;
  const int kbase = blockIdx.z * Kc;
  const int tx = tid & 15, ty = tid >> 4;
  const int lm = tid >> 2, lk = (tid & 3) << 2;
  float acc[4][4] = {};
  for (int k0 = kbase; k0 < kbase + Kc; k0 += 16) {
    float4 av = *reinterpret_cast<const float4*>(A + (size_t)(row0 + lm) * lda + k0 + lk);
    float4 wv = *reinterpret_cast<const float4*>(W + (size_t)(col0 + lm) * ldw + k0 + lk);
    __syncthreads();
    As[lk+0][lm]=av.x; As[lk+1][lm]=av.y; As[lk+2][lm]=av.z; As[lk+3][lm]=av.w;
    Ws[lk+0][lm]=wv.x; Ws[lk+1][lm]=wv.y; Ws[lk+2][lm]=wv.z; Ws[lk+3][lm]=wv.w;
    __syncthreads();
    #pragma unroll
    for (int k = 0; k < 16; ++k) {
      float a0 = As[k][ty*4+0], a1 = As[k][ty*4+1], a2 = As[k][ty*4+2], a3 = As[k][ty*4+3];
      float b0 = Ws[k][tx*4+0], b1 = Ws[k][tx*4+1], b2 = Ws[k][tx*4+2], b3 = Ws[k][tx*4+3];
      acc[0][0] += a0*b0; acc[0][1] += a0*b1; acc[0][2] += a0*b2; acc[0][3] += a0*b3;
      acc[1][0] += a1*b0; acc[1][1] += a1*b1; acc[1][2] += a1*b2; acc[1][3] += a1*b3;
      acc[2][0] += a2*b0; acc[2][1] += a2*b1; acc[2][2] += a2*b2; acc[2][3] += a2*b3;
      acc[3][0] += a3*b0; acc[3][1] += a3*b1; acc[3][2] += a3*b2; acc[3][3] += a3*b3;
    }
  }
  float* base = partials + (size_t)blockIdx.z * M * ldc;
  #pragma unroll
  for (int i = 0; i < 4; ++i) {
    const int r = row0 + ty*4 + i;
    float4 v = make_float4(acc[i][0], acc[i][1], acc[i][2], acc[i][3]);
    *reinterpret_cast<float4*>(base + (size_t)r * ldc + col0 + tx*4) = v;
  }
}

// reduce KSPL partials -> C
__global__ __launch_bounds__(256) void sk_reduce_k(
    const float* __restrict__ partials, float* __restrict__ C, int elems)
{
  const int i = (blockIdx.x * 256 + threadIdx.x) * 4;
  if (i >= elems) return;
  float4 s = *reinterpret_cast<const float4*>(partials + i);
  #pragma unroll
  for (int z = 1; z < KSPL; ++z) {
    const float4 p = *reinterpret_cast<const float4*>(partials + (size_t)z * elems + i);
    s.x += p.x; s.y += p.y; s.z += p.z; s.w += p.w;
  }
  *reinterpret_cast<float4*>(C + i) = s;
}

// layernorm, fp32 out (final LN)
__global__ __launch_bounds__(256) void layernorm_k(
    const float* __restrict__ x, const float* __restrict__ g,
    const float* __restrict__ b, float* __restrict__ out)
{
  __shared__ float red[8];
  const int row = blockIdx.x;
  const int tid = threadIdx.x;
  const float* xr = x + (size_t)row * D_;
  float4 v = *reinterpret_cast<const float4*>(xr + tid * 4);
  float s = v.x + v.y + v.z + v.w;
  #pragma unroll
  for (int off = 32; off; off >>= 1) s += __shfl_down(s, off, 64);
  if ((tid & 63) == 0) red[tid >> 6] = s;
  __syncthreads();
  const float m = (red[0] + red[1] + red[2] + red[3]) * (1.f / D_);
  float dx0 = v.x - m, dx1 = v.y - m, dx2 = v.z - m, dx3 = v.w - m;
  float ss = dx0*dx0 + dx1*dx1 + dx2*dx2 + dx3*dx3;
  #pragma unroll
  for (int off = 32; off; off >>= 1) ss += __shfl_down(ss, off, 64);
  if ((tid & 63) == 0) red[4 + (tid >> 6)] = ss;
  __syncthreads();
  const float var = (red[4] + red[5] + red[6] + red[7]) * (1.f / D_);
  const float rs = rsqrtf(var + 1e-5f);
  const int c = tid * 4;
  const float4 gv = *reinterpret_cast<const float4*>(g + c);
  const float4 bv = *reinterpret_cast<const float4*>(b + c);
  float4 o;
  o.x = dx0 * rs * gv.x + bv.x;
  o.y = dx1 * rs * gv.y + bv.y;
  o.z = dx2 * rs * gv.z + bv.z;
  o.w = dx3 * rs * gv.w + bv.w;
  *reinterpret_cast<float4*>(out + (size_t)row * D_ + c) = o;
}

// layernorm with bf16 out (feeds MFMA GEMM)
__global__ __launch_bounds__(256) void layernorm_bf_k(
    const float* __restrict__ x, const float* __restrict__ g,
    const float* __restrict__ b, __bf16* __restrict__ out)
{
  __shared__ float red[8];
  const int row = blockIdx.x;
  const int tid = threadIdx.x;
  const float* xr = x + (size_t)row * D_;
  float4 v = *reinterpret_cast<const float4*>(xr + tid * 4);
  float s = v.x + v.y + v.z + v.w;
  #pragma unroll
  for (int off = 32; off; off >>= 1) s += __shfl_down(s, off, 64);
  if ((tid & 63) == 0) red[tid >> 6] = s;
  __syncthreads();
  const float m = (red[0] + red[1] + red[2] + red[3]) * (1.f / D_);
  float dx0 = v.x - m, dx1 = v.y - m, dx2 = v.z - m, dx3 = v.w - m;
  float ss = dx0*dx0 + dx1*dx1 + dx2*dx2 + dx3*dx3;
  #pragma unroll
  for (int off = 32; off; off >>= 1) ss += __shfl_down(ss, off, 64);
  if ((tid & 63) == 0) red[4 + (tid >> 6)] = ss;
  __syncthreads();
  const float var = (red[4] + red[5] + red[6] + red[7]) * (1.f / D_);
  const float rs = rsqrtf(var + 1e-5f);
  const int c = tid * 4;
  const float4 gv = *reinterpret_cast<const float4*>(g + c);
  const float4 bv = *reinterpret_cast<const float4*>(b + c);
  bf16_4 o;
  o[0] = (__bf16)(dx0 * rs * gv.x + bv.x);
  o[1] = (__bf16)(dx1 * rs * gv.y + bv.y);
  o[2] = (__bf16)(dx2 * rs * gv.z + bv.z);
  o[3] = (__bf16)(dx3 * rs * gv.w + bv.w);
  *reinterpret_cast<bf16_4*>(out + (size_t)row * D_ + c) = o;
}

// depthwise causal conv K=4 + bias + silu
__global__ __launch_bounds__(256) void conv_silu_k(
    const float* __restrict__ xz, const float* __restrict__ cw,
    const float* __restrict__ cb, float* __restrict__ u)
{
  const int e = blockIdx.x * 256 + threadIdx.x;
  const int t = blockIdx.y;
  const float w0 = cw[e*4+0], w1 = cw[e*4+1], w2 = cw[e*4+2], w3 = cw[e*4+3];
  float acc = cb[e];
  if (t >= 3) acc += w0 * xz[(size_t)(t-3) * (2*ED_) + e];
  if (t >= 2) acc += w1 * xz[(size_t)(t-2) * (2*ED_) + e];
  if (t >= 1) acc += w2 * xz[(size_t)(t-1) * (2*ED_) + e];
  acc += w3 * xz[(size_t)t * (2*ED_) + e];
  u[(size_t)t * ED_ + e] = silu_f(acc);
}

// ---- chunked selective scan ----
__global__ __launch_bounds__(256) void scan_phase1(
    const float* __restrict__ delta, const float* __restrict__ u,
    const float* __restrict__ xdbl, const float* __restrict__ A_log,
    float* __restrict__ hend, float* __restrict__ Pend)
{
  const int tid = threadIdx.x;
  const int n = tid & 31;
  const int e = blockIdx.x * 8 + (tid >> 5);
  const int c = blockIdx.y;
  const float a = -expf(A_log[e * NST + n]);
  float h = 0.f, S = 0.f;
  const int t0 = c * CHUNK;
  #pragma unroll 8
  for (int t = t0; t < t0 + CHUNK; ++t) {
    const float sd = delta[(size_t)t * ED_ + e];
    const float uv = u[(size_t)t * ED_ + e];
    const float Bv = xdbl[(size_t)t * 128 + 64 + n];
    const float dA = __expf(sd * a);
    h = fmaf(dA, h, sd * uv * Bv);
    S += sd;
  }
  const int idx = c * (ED_ * NST) + blockIdx.x * 256 + tid;
  hend[idx] = h;
  Pend[idx] = __expf(a * S);
}

__global__ __launch_bounds__(256) void scan_phase2(
    const float* __restrict__ hend, float* __restrict__ Pend_hin)
{
  const int idx = blockIdx.x * 256 + threadIdx.x;
  float hc = 0.f;
  #pragma unroll
  for (int c = 0; c < NCH; ++c) {
    const int off = c * (ED_ * NST) + idx;
    const float P = Pend_hin[off];
    const float hn = hend[off];
    Pend_hin[off] = hc;
    hc = fmaf(P, hc, hn);
  }
}

// phase 3: re-scan from true h_in; LDS-transpose deferred n-reduction
__global__ __launch_bounds__(256, 4) void scan_phase3(
    const float* __restrict__ delta, const float* __restrict__ u,
    const float* __restrict__ xdbl, const float* __restrict__ A_log,
    const float* __restrict__ hin, const float* __restrict__ Dp,
    const float* __restrict__ xz, __bf16* __restrict__ y)
{
  __shared__ float p_lds[8][32][33];
  const int tid = threadIdx.x;
  const int n = tid & 31;
  const int c = tid >> 5;
  const int e = blockIdx.x * 8 + c;
  const int ch = blockIdx.y;
  const float a = -expf(A_log[e * NST + n]);
  const float dp = Dp[e];
  float h = hin[ch * (ED_ * NST) + blockIdx.x * 256 + tid];
  const int t0 = ch * CHUNK;
  for (int tb = 0; tb < CHUNK; tb += 32) {
    #pragma unroll 8
    for (int j = 0; j < 32; ++j) {
      const int t = t0 + tb + j;
      const float sd = delta[(size_t)t * ED_ + e];
      const float uv = u[(size_t)t * ED_ + e];
      const float Bv = xdbl[(size_t)t * 128 + 64 + n];
      const float Cv = xdbl[(size_t)t * 128 + 96 + n];
      const float dA = __expf(sd * a);
      h = fmaf(dA, h, sd * uv * Bv);
      p_lds[c][j][n] = h * Cv;
    }
    __syncthreads();
    float s = 0.f;
    #pragma unroll
    for (int k = 0; k < 32; ++k) s += p_lds[c][n][k];
    const int t = t0 + tb + n;
    const float uvt = u[(size_t)t * ED_ + e];
    const float zv = xz[(size_t)t * (2*ED_) + ED_ + e];
    y[(size_t)t * ED_ + e] = (__bf16)((s + uvt * dp) * silu_f(zv));
    __syncthreads();
  }
}

__global__ __launch_bounds__(256) void colmean_k(const float* __restrict__ hf, float* __restrict__ cm)
{
  const int d = blockIdx.x * 256 + threadIdx.x;
  float s = 0.f;
  for (int t = 0; t < L_; ++t) s += hf[(size_t)t * D_ + d];
  cm[d] = s * (1.f / L_);
}

__global__ __launch_bounds__(256) void state_k(
    const float* __restrict__ cm, const float* __restrict__ spw,
    const float* __restrict__ spb, float* __restrict__ out)
{
  __shared__ float red[4];
  const int nidx = blockIdx.x;
  const int tid = threadIdx.x;
  float s = 0.f;
  for (int d = tid; d < D_; d += 256) s += cm[d] * spw[(size_t)nidx * D_ + d];
  #pragma unroll
  for (int off = 32; off; off >>= 1) s += __shfl_down(s, off, 64);
  if ((tid & 63) == 0) red[tid >> 6] = s;
  __syncthreads();
  if (tid == 0) out[nidx] = red[0] + red[1] + red[2] + red[3] + spb[nidx];
}

extern "C" void kernel_launch(void* const* d_in, const int* in_sizes, int n_in,
                              void* d_out, int out_size, void* d_ws, size_t ws_size,
                              hipStream_t stream) {
  const float* x        = (const float*)d_in[0];
  const float* Wi       = (const float*)d_in[1];
  const float* bi       = (const float*)d_in[2];
  const float* ln_g     = (const float*)d_in[3];
  const float* ln_b     = (const float*)d_in[4];
  const float* in_w     = (const float*)d_in[5];
  const float* conv_w   = (const float*)d_in[6];
  const float* conv_b   = (const float*)d_in[7];
  const float* xproj_w  = (const float*)d_in[8];
  const float* dtproj_w = (const float*)d_in[9];
  const float* dtproj_b = (const float*)d_in[10];
  const float* A_log    = (const float*)d_in[11];
  const float* Dp       = (const float*)d_in[12];
  const float* out_w    = (const float*)d_in[13];
  const float* fn_g     = (const float*)d_in[14];
  const float* fn_b     = (const float*)d_in[15];
  const float* sp_w     = (const float*)d_in[16];
  const float* sp_b     = (const float*)d_in[17];
  float* out  = (float*)d_out;
  float* ws_f = (float*)d_ws;

  float* h_buf  = ws_f;                // 1048576
  float* xz     = ws_f + 1048576;      // 4194304
  float* u_buf  = ws_f + 5242880;      // 2097152
  float* xdbl   = ws_f + 7340032;      // 131072
  float* delta  = ws_f + 7471104;      // 2097152
  float* hend   = ws_f + 9568256;      // 524288
  float* pend   = ws_f + 10092544;     // 524288
  float* cmean  = ws_f + 10616832;     // 1024
  __bf16* nbf   = (__bf16*)(ws_f + 10617856);  // 1M bf16
  __bf16* ybf   = (__bf16*)(ws_f + 11142144);  // 2M bf16
  __bf16* wbf   = (__bf16*)(ws_f + 12190720);  // 4.19M bf16
  // xproj split-K partials: overlays hend+pend (dead until scan_phase1)
  float* skpart = hend;                // KSPL * 1024 * 128 = 1048576
  // MFMA split-K partials (4 * 1024*1024 floats): overlays u_buf/xdbl/delta,
  // which are dead at both use-sites (before loop; after scan_phase3)
  float* skmf   = u_buf;               // 4194304 floats, ends at 9437184 < 9568256

  const dim3 blk(256);

  // h = x @ Wi^T + bi   (bf16 MFMA, split-K=4)
  f2bf_k<<<512, blk, 0, stream>>>(x, nbf, L_ * D_);
  f2bf_k<<<512, blk, 0, stream>>>(Wi, wbf, D_ * D_);
  gemm_mfma_sk<<<dim3(D_/128, L_/128, ZSPL), blk, 0, stream>>>(
      nbf, wbf, skmf, L_, D_, D_, D_/ZSPL);
  mfma_sk_reduce<<<dim3(L_*D_/4/256), blk, 0, stream>>>(
      skmf, bi, h_buf, L_*D_, D_, 4);

  for (int i = 0; i < NB_; ++i) {
    layernorm_bf_k<<<L_, blk, 0, stream>>>(h_buf, ln_g + i*D_, ln_b + i*D_, nbf);
    // xz = normed @ in_w^T  (256 blocks, no split needed)
    f2bf_k<<<2048, blk, 0, stream>>>(in_w + (size_t)i*2*ED_*D_, wbf, 2*ED_*D_);
    gemm_mfma<<<dim3(2*ED_/128, L_/128), blk, 0, stream>>>(nbf, wbf, nullptr, xz, 2*ED_, D_, 0);
    conv_silu_k<<<dim3(ED_/256, L_), blk, 0, stream>>>(
        xz, conv_w + (size_t)i*ED_*KCONV, conv_b + (size_t)i*ED_, u_buf);
    // x_dbl = u @ xproj^T  (fp32 split-K over 8 chunks)
    gemm_bt_sk<<<dim3(128/64, L_/64, KSPL), blk, 0, stream>>>(
        u_buf, ED_, xproj_w + (size_t)i*128*ED_, ED_, skpart, 128, L_, 128, ED_);
    sk_reduce_k<<<dim3(L_*128/4/256), blk, 0, stream>>>(skpart, xdbl, L_ * 128);
    // delta = softplus(dt @ dtproj^T + b)  (fp32, K=64)
    gemm_bt<<<dim3(ED_/64, L_/64), blk, 0, stream>>>(
        xdbl, 128, dtproj_w + (size_t)i*ED_*DTR_, DTR_, dtproj_b + (size_t)i*ED_,
        delta, ED_, L_, ED_, DTR_, 4 | 2);
    // chunked scan
    scan_phase1<<<dim3(ED_/8, NCH), blk, 0, stream>>>(
        delta, u_buf, xdbl, A_log + (size_t)i*ED_*NST, hend, pend);
    scan_phase2<<<dim3(ED_*NST/256), blk, 0, stream>>>(hend, pend);
    scan_phase3<<<dim3(ED_/8, NCH), blk, 0, stream>>>(
        delta, u_buf, xdbl, A_log + (size_t)i*ED_*NST, pend,
        Dp + (size_t)i*ED_, xz, ybf);
    // h += y @ out_w^T   (bf16 MFMA, split-K=4; partials overlay dead bufs)
    f2bf_k<<<1024, blk, 0, stream>>>(out_w + (size_t)i*D_*ED_, wbf, D_*ED_);
    gemm_mfma_sk<<<dim3(D_/128, L_/128, ZSPL), blk, 0, stream>>>(
        ybf, wbf, skmf, L_, D_, ED_, ED_/ZSPL);
    mfma_sk_reduce<<<dim3(L_*D_/4/256), blk, 0, stream>>>(
        skmf, nullptr, h_buf, L_*D_, D_, 1);
  }

  layernorm_k<<<L_, blk, 0, stream>>>(h_buf, fn_g, fn_b, out);
  colmean_k<<<D_/256, blk, 0, stream>>>(out, cmean);
  state_k<<<NST, blk, 0, stream>>>(cmean, sp_w, sp_b, out + (size_t)L_*D_);
}